// Round 9
// baseline (1486.912 us; speedup 1.0000x reference)
//
#include <hip/hip_runtime.h>
#include <hip/hip_bf16.h>

typedef __attribute__((ext_vector_type(8))) short bf16x8;
typedef __attribute__((ext_vector_type(4))) float f32x4;

__device__ __forceinline__ float bf2f(short u) {
  union { unsigned int u; float f; } c;
  c.u = ((unsigned int)(unsigned short)u) << 16;
  return c.f;
}
__device__ __forceinline__ short f2bf(float f) {
  union { float f; unsigned int u; } c; c.f = f;
  unsigned int r = (c.u + 0x7fffu + ((c.u >> 16) & 1u)) >> 16;
  return (short)(unsigned short)r;
}

__device__ __forceinline__ void gload16(const void* g, void* l) {
  __builtin_amdgcn_global_load_lds(
      (const __attribute__((address_space(1))) unsigned int*)g,
      (__attribute__((address_space(3))) unsigned int*)l, 16, 0, 0);
}

__device__ __forceinline__ void gload_reg(const void* p, f32x4* d) {
  asm volatile("global_load_dwordx4 %0, %1, off"
               : "=&v"(*d) : "v"(p) : "memory");
}

// exp of 2 packed bf16 (one dword), scale, repack to 2 bf16
__device__ __forceinline__ unsigned expack(unsigned d, float M, float I) {
  union { unsigned u; float f; } lo, hi;
  lo.u = d << 16;
  hi.u = d & 0xffff0000u;
  float a = __expf(lo.f - M) * I;
  float b = __expf(hi.f - M) * I;
  unsigned ra = (unsigned)(unsigned short)f2bf(a);
  unsigned rb = (unsigned)(unsigned short)f2bf(b);
  return ra | (rb << 16);
}

// ---------------- fp32 -> bf16 convert ----------------
__global__ __launch_bounds__(256) void cvt_k(const float* __restrict__ in,
                                             short* __restrict__ out, int n4) {
  int i = blockIdx.x * blockDim.x + threadIdx.x;
  const int stride = gridDim.x * blockDim.x;
  for (; i < n4; i += stride) {
    float4 v = ((const float4*)in)[i];
    short4 o;
    o.x = f2bf(v.x); o.y = f2bf(v.y); o.z = f2bf(v.z); o.w = f2bf(v.w);
    ((short4*)out)[i] = o;
  }
}

// ---------------- W [1024][1024] f32 -> W^T bf16 ----------------
__global__ __launch_bounds__(256) void cvtT_k(const float* __restrict__ W,
                                              short* __restrict__ Wt) {
  __shared__ float tile[32][33];
  const int n0 = blockIdx.x * 32, k0 = blockIdx.y * 32;
  const int tr = threadIdx.x >> 5;
  const int tc = threadIdx.x & 31;
#pragma unroll
  for (int p = 0; p < 4; ++p)
    tile[p * 8 + tr][tc] = W[(long long)(k0 + p * 8 + tr) * 1024 + n0 + tc];
  __syncthreads();
#pragma unroll
  for (int p = 0; p < 4; ++p)
    Wt[(long long)(n0 + p * 8 + tr) * 1024 + k0 + tc] = f2bf(tile[tc][p * 8 + tr]);
}

// =====================================================================
// 256x128x32 bf16 MFMA GEMM, triple-buffered (72 KiB LDS, 2 blocks/CU)
// (R8 core, validated).  EPI 0: bf16 +bias[col]; EPI 1: bf16 *scale AND
// per-row softmax partials (m, sum_exp) over this block's 128 cols ->
// Pm/Ps[z][row][bx]; EPI 3: V^T layout.
// =====================================================================

template<int EPI>
__global__ __launch_bounds__(512, 4) void gemm8_k(
    const short* __restrict__ A, const short* __restrict__ Bt,
    void* __restrict__ Cv, const float* __restrict__ X,
    int K, int lda, int ldb, int ldc,
    long long strA, long long strB, long long strC, long long strX, float scale,
    float* __restrict__ Pm, float* __restrict__ Ps) {
  __shared__ __align__(16) short Ls[36864];   // 72 KiB

  const int lane = threadIdx.x & 63;
  const int w = threadIdx.x >> 6;       // 0..7
  const int wm = w >> 1, wn = w & 1;
  const int l15 = lane & 15;
  const int g4 = lane >> 4;             // 0..3 = k-chunk
  const int swR = ((g4 ^ ((l15 >> 1) & 3)) << 3);
  const int arow = (wm * 64 + l15) * 32 + swR;
  const int brow = (wn * 64 + l15) * 32 + swR;
  const int sg = (lane & 3) ^ ((lane >> 3) & 3);

  // XCD-aware bijective block swizzle (nwg % 8 == 0)
  const int gx = gridDim.x, gy = gridDim.y;
  const int nwg = gx * gy * gridDim.z;
  int lid = blockIdx.x + gx * (blockIdx.y + gy * blockIdx.z);
  lid = (lid & 7) * (nwg >> 3) + (lid >> 3);
  const int bx = lid % gx;
  const int rem = lid / gx;
  const int by = rem % gy;
  const int bz = rem / gy;

  const int n0 = bx * 128;
  const int m0 = by * 256;
  const int nt = K >> 5;

  const long long ldaB = 2LL * lda, ldbB = 2LL * ldb;
  const long long ldaB16 = 16 * ldaB;

  const char* pA = (const char*)(A + (long long)bz * strA)
      + (long long)(m0 + w * 32 + (lane >> 2)) * ldaB + sg * 16;
  const char* pB = (const char*)(Bt + (long long)bz * strB)
      + (long long)(n0 + w * 16 + (lane >> 2)) * ldbB + sg * 16;

  short* dA = Ls + w * 1024;            // + buf*12288
  short* dB = Ls + 8192 + w * 512;      // + buf*12288

  f32x4 acc[4][4] = {};

  // prologue: stage tiles 0,1,2 -> buffers 0,1,2
#pragma unroll
  for (int i = 0; i < 3; ++i) {
    const char* qA = pA + i * 64;
    gload16(qA,           dA + i * 12288);
    gload16(qA + ldaB16,  dA + i * 12288 + 512);
    gload16(pB + i * 64,  dB + i * 12288);
  }
  asm volatile("s_waitcnt vmcnt(6)" ::: "memory");
  __builtin_amdgcn_s_barrier();

  int cur = 0;
  for (int t = 0; t < nt; ++t) {
    const int bufO = cur * 12288;
    bf16x8 aR[4], bR[4];
#pragma unroll
    for (int mi = 0; mi < 4; ++mi)
      aR[mi] = *(const bf16x8*)(Ls + bufO + arow + mi * 512);
#pragma unroll
    for (int ni = 0; ni < 4; ++ni)
      bR[ni] = *(const bf16x8*)(Ls + bufO + 8192 + brow + ni * 512);
    asm volatile("s_waitcnt lgkmcnt(0)" ::: "memory");
    __builtin_amdgcn_s_barrier();
    if (t + 3 < nt) {
      const char* qA = pA + (t + 3) * 64;
      gload16(qA,          dA + bufO);
      gload16(qA + ldaB16, dA + bufO + 512);
      gload16(pB + (t + 3) * 64, dB + bufO);
    }
    __builtin_amdgcn_sched_barrier(0);
    __builtin_amdgcn_s_setprio(1);
#pragma unroll
    for (int mi = 0; mi < 4; ++mi)
#pragma unroll
      for (int ni = 0; ni < 4; ++ni)
        acc[mi][ni] = __builtin_amdgcn_mfma_f32_16x16x32_bf16(
            aR[mi], bR[ni], acc[mi][ni], 0, 0, 0);
    __builtin_amdgcn_s_setprio(0);
    if (t + 3 < nt)      asm volatile("s_waitcnt vmcnt(6)" ::: "memory");
    else if (t + 2 < nt) asm volatile("s_waitcnt vmcnt(3)" ::: "memory");
    else                 asm volatile("s_waitcnt vmcnt(0)" ::: "memory");
    __builtin_amdgcn_s_barrier();
    cur = (cur == 2) ? 0 : cur + 1;
  }

  // ---- epilogue ----
  const int rB = g4 * 4;
  if (EPI == 0) {
    short* C = (short*)Cv + (long long)bz * strC;
#pragma unroll
    for (int ni = 0; ni < 4; ++ni) {
      const int col = n0 + wn * 64 + ni * 16 + l15;
      const float bv = X[col];
#pragma unroll
      for (int mi = 0; mi < 4; ++mi)
#pragma unroll
        for (int r = 0; r < 4; ++r) {
          const int row = m0 + wm * 64 + mi * 16 + rB + r;
          C[(long long)row * ldc + col] = f2bf(acc[mi][ni][r] + bv);
        }
    }
  } else if (EPI == 1) {
    short* C = (short*)Cv + (long long)bz * strC;
#pragma unroll
    for (int ni = 0; ni < 4; ++ni) {
      const int col = n0 + wn * 64 + ni * 16 + l15;
#pragma unroll
      for (int mi = 0; mi < 4; ++mi)
#pragma unroll
        for (int r = 0; r < 4; ++r) {
          const int row = m0 + wm * 64 + mi * 16 + rB + r;
          C[(long long)row * ldc + col] = f2bf(acc[mi][ni][r] * scale);
        }
    }
    // per-row softmax partials over this block's 128 cols
    float mA[16], sA_[16];
#pragma unroll
    for (int mi = 0; mi < 4; ++mi)
#pragma unroll
      for (int r = 0; r < 4; ++r) {
        const int ix = mi * 4 + r;
        float v0 = acc[mi][0][r] * scale, v1 = acc[mi][1][r] * scale;
        float v2 = acc[mi][2][r] * scale, v3 = acc[mi][3][r] * scale;
        float m = fmaxf(fmaxf(v0, v1), fmaxf(v2, v3));
        float s = __expf(v0 - m) + __expf(v1 - m) + __expf(v2 - m) + __expf(v3 - m);
#pragma unroll
        for (int o = 1; o < 16; o <<= 1) {
          float mo = __shfl_xor(m, o), so = __shfl_xor(s, o);
          float M = fmaxf(m, mo);
          s = s * __expf(m - M) + so * __expf(mo - M);
          m = M;
        }
        mA[ix] = m; sA_[ix] = s;
      }
    float* lm = (float*)Ls;         // [256]
    float* ls2 = lm + 256;          // [256]
    __syncthreads();                // K-loop done for all; LDS reusable
    if (wn == 1 && l15 == 0) {
#pragma unroll
      for (int mi = 0; mi < 4; ++mi)
#pragma unroll
        for (int r = 0; r < 4; ++r) {
          const int lr = wm * 64 + mi * 16 + rB + r;
          lm[lr] = mA[mi * 4 + r]; ls2[lr] = sA_[mi * 4 + r];
        }
    }
    __syncthreads();
    if (wn == 0 && l15 == 0) {
#pragma unroll
      for (int mi = 0; mi < 4; ++mi)
#pragma unroll
        for (int r = 0; r < 4; ++r) {
          const int lr = wm * 64 + mi * 16 + rB + r;
          float m1 = mA[mi * 4 + r], s1 = sA_[mi * 4 + r];
          float m2 = lm[lr], s2 = ls2[lr];
          float M = fmaxf(m1, m2);
          float S = s1 * __expf(m1 - M) + s2 * __expf(m2 - M);
          const long long pidx = ((long long)bz * 2048 + m0 + lr) * 16 + bx;
          Pm[pidx] = M; Ps[pidx] = S;
        }
    }
  } else {  // EPI == 3: C = V^T, [b][f=row][s], n = b*2048 + s
    short* C = (short*)Cv;
#pragma unroll
    for (int ni = 0; ni < 4; ++ni) {
      const int col = n0 + wn * 64 + ni * 16 + l15;
      const int b2 = col >> 11;
      const int s = col & 2047;
#pragma unroll
      for (int mi = 0; mi < 4; ++mi)
#pragma unroll
        for (int r = 0; r < 4; ++r) {
          const int row = m0 + wm * 64 + mi * 16 + rB + r;
          C[(long long)b2 * 2097152 + (long long)row * 2048 + s] =
              f2bf(acc[mi][ni][r] + X[row]);
        }
    }
  }
}

// =====================================================================
// pv_k: fused softmax + PV + residual.
// A = raw scaled logits Sl; per-block row stats (M, 1/(S+eps)) reduced
// from QK^T partials; A staged via reg-load + exp + ds_write (double
// buffer, 1-tile-held named gen regs); B = Vt via gload_lds.
// out[m][f] = sum_s P[m][s] * V[s][f] + x[m][f]
// =====================================================================

#define PVSTA(GA, GB, DST) do { \
  uint4 ua = *(uint4*)&(GA); \
  uint4 ub = *(uint4*)&(GB); \
  uint4 wa, wb; \
  wa.x = expack(ua.x, M0, I0); wa.y = expack(ua.y, M0, I0); \
  wa.z = expack(ua.z, M0, I0); wa.w = expack(ua.w, M0, I0); \
  wb.x = expack(ub.x, M1, I1); wb.y = expack(ub.y, M1, I1); \
  wb.z = expack(ub.z, M1, I1); wb.w = expack(ub.w, M1, I1); \
  *(uint4*)((DST) + lane * 8) = wa; \
  *(uint4*)((DST) + 512 + lane * 8) = wb; \
} while (0)

#define PVTILE(T, BUFO, OBUF, GA, GB, OGA, OGB) do { \
  bf16x8 aR[4], bR[4]; \
  _Pragma("unroll") \
  for (int mi = 0; mi < 4; ++mi) aR[mi] = *(const bf16x8*)(Ls + (BUFO) + arow + mi * 512); \
  _Pragma("unroll") \
  for (int ni = 0; ni < 4; ++ni) bR[ni] = *(const bf16x8*)(Ls + (BUFO) + 8192 + brow + ni * 512); \
  asm volatile("s_waitcnt lgkmcnt(0)" ::: "memory"); \
  __builtin_amdgcn_s_barrier(); \
  if ((T) + 2 < nt) { \
    gload_reg(pA + ((T) + 2) * 64, &(GA)); \
    gload_reg(pA + ((T) + 2) * 64 + ldaB16, &(GB)); \
    gload16(pB + ((T) + 2) * 64, dB + (BUFO)); \
    asm volatile("s_waitcnt vmcnt(3)" ::: "memory"); \
  } else { \
    asm volatile("s_waitcnt vmcnt(0)" ::: "memory"); \
  } \
  __builtin_amdgcn_sched_barrier(0); \
  if ((T) + 1 < nt) { PVSTA(OGA, OGB, dA + (OBUF)); } \
  __builtin_amdgcn_s_setprio(1); \
  _Pragma("unroll") \
  for (int mi = 0; mi < 4; ++mi) \
    _Pragma("unroll") \
    for (int ni = 0; ni < 4; ++ni) \
      acc[mi][ni] = __builtin_amdgcn_mfma_f32_16x16x32_bf16(aR[mi], bR[ni], acc[mi][ni], 0, 0, 0); \
  __builtin_amdgcn_s_setprio(0); \
  asm volatile("s_waitcnt lgkmcnt(0)" ::: "memory"); \
  __builtin_amdgcn_s_barrier(); \
} while (0)

__global__ __launch_bounds__(512, 4) void pv_k(
    const short* __restrict__ Sl, const short* __restrict__ Vt,
    float* __restrict__ Out, const float* __restrict__ x,
    const float* __restrict__ Pm, const float* __restrict__ Ps) {
  __shared__ __align__(16) short Ls[24576];   // 48KB: 2 bufs x (A 8192 + B 4096)
  __shared__ float rs[256][2];

  const int lane = threadIdx.x & 63;
  const int w = threadIdx.x >> 6;
  const int wm = w >> 1, wn = w & 1;
  const int l15 = lane & 15;
  const int g4 = lane >> 4;
  const int swR = ((g4 ^ ((l15 >> 1) & 3)) << 3);
  const int arow = (wm * 64 + l15) * 32 + swR;
  const int brow = (wn * 64 + l15) * 32 + swR;
  const int sg = (lane & 3) ^ ((lane >> 3) & 3);

  const int nwg = 1024;                 // grid (8,8,16)
  int lid = blockIdx.x + 8 * (blockIdx.y + 8 * blockIdx.z);
  lid = (lid & 7) * (nwg >> 3) + (lid >> 3);
  const int bx = lid % 8;
  const int rem = lid / 8;
  const int by = rem % 8;
  const int bz = rem / 8;
  const int n0 = bx * 128, m0 = by * 256;
  const int nt = 64;                    // K = 2048, BK = 32

  const long long SS = 4194304LL, SD = 2097152LL;
  const long long ldaB = 4096, ldbB = 4096;
  const long long ldaB16 = 16 * ldaB;

  const char* pA = (const char*)(Sl + (long long)bz * SS)
      + (long long)(m0 + w * 32 + (lane >> 2)) * ldaB + sg * 16;
  const char* pB = (const char*)(Vt + (long long)bz * SD)
      + (long long)(n0 + w * 16 + (lane >> 2)) * ldbB + sg * 16;

  short* dA = Ls + w * 1024;            // + buf*12288
  short* dB = Ls + 8192 + w * 512;      // + buf*12288

  // row stats: M = max of partials, I = 1/(sum+eps)
  if (threadIdx.x < 256) {
    const long long base = ((long long)bz * 2048 + m0 + threadIdx.x) * 16;
    float M = -3.0e38f;
#pragma unroll
    for (int j = 0; j < 16; ++j) M = fmaxf(M, Pm[base + j]);
    float S = 0.f;
#pragma unroll
    for (int j = 0; j < 16; ++j) S += Ps[base + j] * __expf(Pm[base + j] - M);
    rs[threadIdx.x][0] = M;
    rs[threadIdx.x][1] = 1.0f / (S + 1e-6f);
  }
  __syncthreads();
  const int r0 = w * 32 + (lane >> 2);
  const float M0 = rs[r0][0],      I0 = rs[r0][1];
  const float M1 = rs[r0 + 16][0], I1 = rs[r0 + 16][1];

  f32x4 acc[4][4] = {};
  f32x4 gA0, gB0, gA1, gB1;

  // prologue: tiles 0 (gen0/buf0), 1 (gen1/buf1)
  gload_reg(pA, &gA0);
  gload_reg(pA + ldaB16, &gB0);
  gload16(pB, dB);
  gload_reg(pA + 64, &gA1);
  gload_reg(pA + 64 + ldaB16, &gB1);
  gload16(pB + 64, dB + 12288);
  asm volatile("s_waitcnt vmcnt(3)" ::: "memory");
  __builtin_amdgcn_sched_barrier(0);
  PVSTA(gA0, gB0, dA);
  asm volatile("s_waitcnt vmcnt(0)" ::: "memory");
  __builtin_amdgcn_sched_barrier(0);
  PVSTA(gA1, gB1, dA + 12288);
  asm volatile("s_waitcnt lgkmcnt(0)" ::: "memory");
  __builtin_amdgcn_s_barrier();

  for (int j = 0; j < 32; ++j) {
    const int t0 = 2 * j;
    PVTILE(t0,     0,     12288, gA0, gB0, gA1, gB1);
    PVTILE(t0 + 1, 12288, 0,     gA1, gB1, gA0, gB0);
  }

  // epilogue: f32 out + residual
  const int rB = g4 * 4;
  float* C = Out + (long long)bz * SD;
  const float* Xb = x + (long long)bz * SD;
#pragma unroll
  for (int ni = 0; ni < 4; ++ni) {
    const int col = n0 + wn * 64 + ni * 16 + l15;
#pragma unroll
    for (int mi = 0; mi < 4; ++mi)
#pragma unroll
      for (int r = 0; r < 4; ++r) {
        const int row = m0 + wm * 64 + mi * 16 + rB + r;
        const long long idx = (long long)row * 1024 + col;
        C[idx] = acc[mi][ni][r] + Xb[idx];
      }
  }
}

extern "C" void kernel_launch(void* const* d_in, const int* in_sizes, int n_in,
                              void* d_out, int out_size, void* d_ws, size_t ws_size,
                              hipStream_t stream) {
  const float* x  = (const float*)d_in[0];
  const float* y  = (const float*)d_in[1];
  const float* Wq = (const float*)d_in[2];
  const float* bq = (const float*)d_in[3];
  const float* Wk = (const float*)d_in[4];
  const float* bk = (const float*)d_in[5];
  const float* Wv = (const float*)d_in[6];
  const float* bv = (const float*)d_in[7];
  float* out = (float*)d_out;

  const long long SD  = 2048LL * 1024;
  const long long BSD = 16LL * SD;
  const long long SS  = 2048LL * 2048;

  char* ws = (char*)d_ws;
  short* xb  = (short*)ws;                   // 67.1 MB
  short* yb  = xb + BSD;                     // 67.1 MB
  short* Sl  = (short*)ws;                   // 134.2 MB (aliases xb+yb; written after they die)
  short* Qb  = (short*)(ws + 134217728);     // 67.1 MB
  short* Kb  = Qb + BSD;                     // 67.1 MB
  short* Vt  = Kb + BSD;                     // 67.1 MB  [b][d][s]
  short* Wqt = Vt + BSD;                     // 2 MB each, at byte 335544320
  short* Wkt = Wqt + 1024 * 1024;
  short* Wvt = Wkt + 1024 * 1024;
  // softmax partials overlay the dead Wqt/Wkt region after projections
  float* Pm = (float*)(ws + 335544320);      // [16][2048][16] f32 = 2 MB
  float* Ps = Pm + 524288;                   // 2 MB

  // 1) convert x, y to bf16
  cvt_k<<<2048, 256, 0, stream>>>(x, xb, (int)(BSD / 4));
  cvt_k<<<2048, 256, 0, stream>>>(y, yb, (int)(BSD / 4));

  // 2) transpose+convert weights
  cvtT_k<<<dim3(32, 32), 256, 0, stream>>>(Wq, Wqt);
  cvtT_k<<<dim3(32, 32), 256, 0, stream>>>(Wk, Wkt);
  cvtT_k<<<dim3(32, 32), 256, 0, stream>>>(Wv, Wvt);

  // 3) Q = xb @ Wq + bq
  gemm8_k<0><<<dim3(8, 128, 1), 512, 0, stream>>>(
      xb, Wqt, Qb, bq, 1024, 1024, 1024, 1024, 0, 0, 0, 0, 1.f, nullptr, nullptr);
  // 4) K = yb @ Wk + bk
  gemm8_k<0><<<dim3(8, 128, 1), 512, 0, stream>>>(
      yb, Wkt, Kb, bk, 1024, 1024, 1024, 1024, 0, 0, 0, 0, 1.f, nullptr, nullptr);
  // 5) V^T: A = Wv^T, Bt = yb -> Vt[b][f][s]
  gemm8_k<3><<<dim3(256, 4, 1), 512, 0, stream>>>(
      Wvt, yb, Vt, bv, 1024, 1024, 1024, 0, 0, 0, 0, 0, 1.f, nullptr, nullptr);

  // 6) logits = Q @ K^T / 32 -> Sl raw; also per-row softmax partials Pm/Ps
  gemm8_k<1><<<dim3(16, 8, 16), 512, 0, stream>>>(
      Qb, Kb, Sl, nullptr, 1024, 1024, 1024, 2048, SD, SD, SS, 0, 0.03125f, Pm, Ps);

  // 7) out = softmax(Sl) @ V + x   (fused softmax in A-staging)
  pv_k<<<dim3(8, 8, 16), 512, 0, stream>>>(Sl, Vt, out, x, Pm, Ps);

  (void)in_sizes; (void)n_in; (void)out_size; (void)ws_size;
}

// Round 12
// 867.221 us; speedup vs baseline: 1.7146x; 1.7146x over previous
//
#include <hip/hip_runtime.h>
#include <hip/hip_bf16.h>

typedef __attribute__((ext_vector_type(8))) short bf16x8;
typedef __attribute__((ext_vector_type(4))) float f32x4;
typedef __attribute__((ext_vector_type(4))) unsigned u32x4;

__device__ __forceinline__ float bf2f(short u) {
  union { unsigned int u; float f; } c;
  c.u = ((unsigned int)(unsigned short)u) << 16;
  return c.f;
}
__device__ __forceinline__ short f2bf(float f) {
  union { float f; unsigned int u; } c; c.f = f;
  unsigned int r = (c.u + 0x7fffu + ((c.u >> 16) & 1u)) >> 16;
  return (short)(unsigned short)r;
}

__device__ __forceinline__ void gload16(const void* g, void* l) {
  __builtin_amdgcn_global_load_lds(
      (const __attribute__((address_space(1))) unsigned int*)g,
      (__attribute__((address_space(3))) unsigned int*)l, 16, 0, 0);
}

// by-value global load (no address-taken locals -> no scratch demotion)
__device__ __forceinline__ u32x4 gload4(const void* p) {
  u32x4 d;
  asm volatile("global_load_dwordx4 %0, %1, off"
               : "=&v"(d) : "v"(p) : "memory");
  return d;
}

// exp of 2 packed bf16 (one dword), scale, repack to 2 bf16
__device__ __forceinline__ unsigned expack(unsigned d, float M, float I) {
  union { unsigned u; float f; } lo, hi;
  lo.u = d << 16;
  hi.u = d & 0xffff0000u;
  float a = __expf(lo.f - M) * I;
  float b = __expf(hi.f - M) * I;
  unsigned ra = (unsigned)(unsigned short)f2bf(a);
  unsigned rb = (unsigned)(unsigned short)f2bf(b);
  return ra | (rb << 16);
}

// ---------------- fp32 -> bf16 convert ----------------
__global__ __launch_bounds__(256) void cvt_k(const float* __restrict__ in,
                                             short* __restrict__ out, int n4) {
  int i = blockIdx.x * blockDim.x + threadIdx.x;
  const int stride = gridDim.x * blockDim.x;
  for (; i < n4; i += stride) {
    float4 v = ((const float4*)in)[i];
    short4 o;
    o.x = f2bf(v.x); o.y = f2bf(v.y); o.z = f2bf(v.z); o.w = f2bf(v.w);
    ((short4*)out)[i] = o;
  }
}

// ---------------- W [1024][1024] f32 -> W^T bf16 ----------------
__global__ __launch_bounds__(256) void cvtT_k(const float* __restrict__ W,
                                              short* __restrict__ Wt) {
  __shared__ float tile[32][33];
  const int n0 = blockIdx.x * 32, k0 = blockIdx.y * 32;
  const int tr = threadIdx.x >> 5;
  const int tc = threadIdx.x & 31;
#pragma unroll
  for (int p = 0; p < 4; ++p)
    tile[p * 8 + tr][tc] = W[(long long)(k0 + p * 8 + tr) * 1024 + n0 + tc];
  __syncthreads();
#pragma unroll
  for (int p = 0; p < 4; ++p)
    Wt[(long long)(n0 + p * 8 + tr) * 1024 + k0 + tc] = f2bf(tile[tc][p * 8 + tr]);
}

// =====================================================================
// 256x128x32 bf16 MFMA GEMM, triple-buffered (72 KiB LDS, 2 blocks/CU)
// (R8 core, validated).  EPI 0: bf16 +bias[col]; EPI 1: bf16 *scale AND
// per-row softmax partials (m, sum_exp) over this block's 128 cols ->
// Pm/Ps[z][row][bx]; EPI 3: V^T layout.
// =====================================================================

template<int EPI>
__global__ __launch_bounds__(512, 4) void gemm8_k(
    const short* __restrict__ A, const short* __restrict__ Bt,
    void* __restrict__ Cv, const float* __restrict__ X,
    int K, int lda, int ldb, int ldc,
    long long strA, long long strB, long long strC, long long strX, float scale,
    float* __restrict__ Pm, float* __restrict__ Ps) {
  __shared__ __align__(16) short Ls[36864];   // 72 KiB

  const int lane = threadIdx.x & 63;
  const int w = threadIdx.x >> 6;       // 0..7
  const int wm = w >> 1, wn = w & 1;
  const int l15 = lane & 15;
  const int g4 = lane >> 4;             // 0..3 = k-chunk
  const int swR = ((g4 ^ ((l15 >> 1) & 3)) << 3);
  const int arow = (wm * 64 + l15) * 32 + swR;
  const int brow = (wn * 64 + l15) * 32 + swR;
  const int sg = (lane & 3) ^ ((lane >> 3) & 3);

  // XCD-aware bijective block swizzle (nwg % 8 == 0)
  const int gx = gridDim.x, gy = gridDim.y;
  const int nwg = gx * gy * gridDim.z;
  int lid = blockIdx.x + gx * (blockIdx.y + gy * blockIdx.z);
  lid = (lid & 7) * (nwg >> 3) + (lid >> 3);
  const int bx = lid % gx;
  const int rem = lid / gx;
  const int by = rem % gy;
  const int bz = rem / gy;

  const int n0 = bx * 128;
  const int m0 = by * 256;
  const int nt = K >> 5;

  const long long ldaB = 2LL * lda, ldbB = 2LL * ldb;
  const long long ldaB16 = 16 * ldaB;

  const char* pA = (const char*)(A + (long long)bz * strA)
      + (long long)(m0 + w * 32 + (lane >> 2)) * ldaB + sg * 16;
  const char* pB = (const char*)(Bt + (long long)bz * strB)
      + (long long)(n0 + w * 16 + (lane >> 2)) * ldbB + sg * 16;

  short* dA = Ls + w * 1024;            // + buf*12288
  short* dB = Ls + 8192 + w * 512;      // + buf*12288

  f32x4 acc[4][4] = {};

  // prologue: stage tiles 0,1,2 -> buffers 0,1,2
#pragma unroll
  for (int i = 0; i < 3; ++i) {
    const char* qA = pA + i * 64;
    gload16(qA,           dA + i * 12288);
    gload16(qA + ldaB16,  dA + i * 12288 + 512);
    gload16(pB + i * 64,  dB + i * 12288);
  }
  asm volatile("s_waitcnt vmcnt(6)" ::: "memory");
  __builtin_amdgcn_s_barrier();

  int cur = 0;
  for (int t = 0; t < nt; ++t) {
    const int bufO = cur * 12288;
    bf16x8 aR[4], bR[4];
#pragma unroll
    for (int mi = 0; mi < 4; ++mi)
      aR[mi] = *(const bf16x8*)(Ls + bufO + arow + mi * 512);
#pragma unroll
    for (int ni = 0; ni < 4; ++ni)
      bR[ni] = *(const bf16x8*)(Ls + bufO + 8192 + brow + ni * 512);
    asm volatile("s_waitcnt lgkmcnt(0)" ::: "memory");
    __builtin_amdgcn_s_barrier();
    if (t + 3 < nt) {
      const char* qA = pA + (t + 3) * 64;
      gload16(qA,          dA + bufO);
      gload16(qA + ldaB16, dA + bufO + 512);
      gload16(pB + (t + 3) * 64, dB + bufO);
    }
    __builtin_amdgcn_sched_barrier(0);
    __builtin_amdgcn_s_setprio(1);
#pragma unroll
    for (int mi = 0; mi < 4; ++mi)
#pragma unroll
      for (int ni = 0; ni < 4; ++ni)
        acc[mi][ni] = __builtin_amdgcn_mfma_f32_16x16x32_bf16(
            aR[mi], bR[ni], acc[mi][ni], 0, 0, 0);
    __builtin_amdgcn_s_setprio(0);
    if (t + 3 < nt)      asm volatile("s_waitcnt vmcnt(6)" ::: "memory");
    else if (t + 2 < nt) asm volatile("s_waitcnt vmcnt(3)" ::: "memory");
    else                 asm volatile("s_waitcnt vmcnt(0)" ::: "memory");
    __builtin_amdgcn_s_barrier();
    cur = (cur == 2) ? 0 : cur + 1;
  }

  // ---- epilogue ----
  const int rB = g4 * 4;
  if (EPI == 0) {
    short* C = (short*)Cv + (long long)bz * strC;
#pragma unroll
    for (int ni = 0; ni < 4; ++ni) {
      const int col = n0 + wn * 64 + ni * 16 + l15;
      const float bv = X[col];
#pragma unroll
      for (int mi = 0; mi < 4; ++mi)
#pragma unroll
        for (int r = 0; r < 4; ++r) {
          const int row = m0 + wm * 64 + mi * 16 + rB + r;
          C[(long long)row * ldc + col] = f2bf(acc[mi][ni][r] + bv);
        }
    }
  } else if (EPI == 1) {
    short* C = (short*)Cv + (long long)bz * strC;
#pragma unroll
    for (int ni = 0; ni < 4; ++ni) {
      const int col = n0 + wn * 64 + ni * 16 + l15;
#pragma unroll
      for (int mi = 0; mi < 4; ++mi)
#pragma unroll
        for (int r = 0; r < 4; ++r) {
          const int row = m0 + wm * 64 + mi * 16 + rB + r;
          C[(long long)row * ldc + col] = f2bf(acc[mi][ni][r] * scale);
        }
    }
    // per-row softmax partials over this block's 128 cols
    float mA[16], sA_[16];
#pragma unroll
    for (int mi = 0; mi < 4; ++mi)
#pragma unroll
      for (int r = 0; r < 4; ++r) {
        const int ix = mi * 4 + r;
        float v0 = acc[mi][0][r] * scale, v1 = acc[mi][1][r] * scale;
        float v2 = acc[mi][2][r] * scale, v3 = acc[mi][3][r] * scale;
        float m = fmaxf(fmaxf(v0, v1), fmaxf(v2, v3));
        float s = __expf(v0 - m) + __expf(v1 - m) + __expf(v2 - m) + __expf(v3 - m);
#pragma unroll
        for (int o = 1; o < 16; o <<= 1) {
          float mo = __shfl_xor(m, o), so = __shfl_xor(s, o);
          float M = fmaxf(m, mo);
          s = s * __expf(m - M) + so * __expf(mo - M);
          m = M;
        }
        mA[ix] = m; sA_[ix] = s;
      }
    float* lm = (float*)Ls;         // [256]
    float* ls2 = lm + 256;          // [256]
    __syncthreads();                // K-loop done for all; LDS reusable
    if (wn == 1 && l15 == 0) {
#pragma unroll
      for (int mi = 0; mi < 4; ++mi)
#pragma unroll
        for (int r = 0; r < 4; ++r) {
          const int lr = wm * 64 + mi * 16 + rB + r;
          lm[lr] = mA[mi * 4 + r]; ls2[lr] = sA_[mi * 4 + r];
        }
    }
    __syncthreads();
    if (wn == 0 && l15 == 0) {
#pragma unroll
      for (int mi = 0; mi < 4; ++mi)
#pragma unroll
        for (int r = 0; r < 4; ++r) {
          const int lr = wm * 64 + mi * 16 + rB + r;
          float m1 = mA[mi * 4 + r], s1 = sA_[mi * 4 + r];
          float m2 = lm[lr], s2 = ls2[lr];
          float M = fmaxf(m1, m2);
          float S = s1 * __expf(m1 - M) + s2 * __expf(m2 - M);
          const long long pidx = ((long long)bz * 2048 + m0 + lr) * 16 + bx;
          Pm[pidx] = M; Ps[pidx] = S;
        }
    }
  } else {  // EPI == 3: C = V^T, [b][f=row][s], n = b*2048 + s
    short* C = (short*)Cv;
#pragma unroll
    for (int ni = 0; ni < 4; ++ni) {
      const int col = n0 + wn * 64 + ni * 16 + l15;
      const int b2 = col >> 11;
      const int s = col & 2047;
#pragma unroll
      for (int mi = 0; mi < 4; ++mi)
#pragma unroll
        for (int r = 0; r < 4; ++r) {
          const int row = m0 + wm * 64 + mi * 16 + rB + r;
          C[(long long)b2 * 2097152 + (long long)row * 2048 + s] =
              f2bf(acc[mi][ni][r] + X[row]);
        }
    }
  }
}

// =====================================================================
// pv_k: fused softmax + PV + residual (scratch-free rebuild of R9).
// A = raw scaled logits Sl; row stats (M, 1/(S+eps)) from QK^T partials;
// A staged via by-value reg loads + exp + ds_write (double buffer);
// B = Vt via gload_lds.  launch_bounds(512,2): 256-reg budget, no spill.
// =====================================================================

#define PVSTA(GA, GB, DST) do { \
  u32x4 wa, wb; \
  wa[0] = expack((GA)[0], M0, I0); wa[1] = expack((GA)[1], M0, I0); \
  wa[2] = expack((GA)[2], M0, I0); wa[3] = expack((GA)[3], M0, I0); \
  wb[0] = expack((GB)[0], M1, I1); wb[1] = expack((GB)[1], M1, I1); \
  wb[2] = expack((GB)[2], M1, I1); wb[3] = expack((GB)[3], M1, I1); \
  *(u32x4*)((DST) + lane * 8) = wa; \
  *(u32x4*)((DST) + 512 + lane * 8) = wb; \
} while (0)

#define PVTILE(T, BUFO, OBUF, GA, GB, OGA, OGB) do { \
  bf16x8 aR[4], bR[4]; \
  _Pragma("unroll") \
  for (int mi = 0; mi < 4; ++mi) aR[mi] = *(const bf16x8*)(Ls + (BUFO) + arow + mi * 512); \
  _Pragma("unroll") \
  for (int ni = 0; ni < 4; ++ni) bR[ni] = *(const bf16x8*)(Ls + (BUFO) + 8192 + brow + ni * 512); \
  asm volatile("s_waitcnt lgkmcnt(0)" ::: "memory"); \
  __builtin_amdgcn_s_barrier(); \
  if ((T) + 2 < nt) { \
    GA = gload4(pA + ((T) + 2) * 64); \
    GB = gload4(pA + ((T) + 2) * 64 + ldaB16); \
    gload16(pB + ((T) + 2) * 64, dB + (BUFO)); \
    asm volatile("s_waitcnt vmcnt(3)" ::: "memory"); \
  } else { \
    asm volatile("s_waitcnt vmcnt(0)" ::: "memory"); \
  } \
  __builtin_amdgcn_sched_barrier(0); \
  if ((T) + 1 < nt) { PVSTA(OGA, OGB, dA + (OBUF)); } \
  __builtin_amdgcn_s_setprio(1); \
  _Pragma("unroll") \
  for (int mi = 0; mi < 4; ++mi) \
    _Pragma("unroll") \
    for (int ni = 0; ni < 4; ++ni) \
      acc[mi][ni] = __builtin_amdgcn_mfma_f32_16x16x32_bf16(aR[mi], bR[ni], acc[mi][ni], 0, 0, 0); \
  __builtin_amdgcn_s_setprio(0); \
  asm volatile("s_waitcnt lgkmcnt(0)" ::: "memory"); \
  __builtin_amdgcn_s_barrier(); \
} while (0)

__global__ __launch_bounds__(512, 2) void pv_k(
    const short* __restrict__ Sl, const short* __restrict__ Vt,
    float* __restrict__ Out, const float* __restrict__ x,
    const float* __restrict__ Pm, const float* __restrict__ Ps) {
  __shared__ __align__(16) short Ls[24576];   // 48KB: 2 bufs x (A 8192 + B 4096)
  __shared__ float rs[256][2];

  const int lane = threadIdx.x & 63;
  const int w = threadIdx.x >> 6;
  const int wm = w >> 1, wn = w & 1;
  const int l15 = lane & 15;
  const int g4 = lane >> 4;
  const int swR = ((g4 ^ ((l15 >> 1) & 3)) << 3);
  const int arow = (wm * 64 + l15) * 32 + swR;
  const int brow = (wn * 64 + l15) * 32 + swR;
  const int sg = (lane & 3) ^ ((lane >> 3) & 3);

  const int nwg = 1024;                 // grid (8,8,16)
  int lid = blockIdx.x + 8 * (blockIdx.y + 8 * blockIdx.z);
  lid = (lid & 7) * (nwg >> 3) + (lid >> 3);
  const int bx = lid % 8;
  const int rem = lid / 8;
  const int by = rem % 8;
  const int bz = rem / 8;
  const int n0 = bx * 128, m0 = by * 256;
  const int nt = 64;                    // K = 2048, BK = 32

  const long long SS = 4194304LL, SD = 2097152LL;
  const long long ldaB = 4096, ldbB = 4096;
  const long long ldaB16 = 16 * ldaB;

  const char* pA = (const char*)(Sl + (long long)bz * SS)
      + (long long)(m0 + w * 32 + (lane >> 2)) * ldaB + sg * 16;
  const char* pB = (const char*)(Vt + (long long)bz * SD)
      + (long long)(n0 + w * 16 + (lane >> 2)) * ldbB + sg * 16;

  short* dA = Ls + w * 1024;            // + buf*12288
  short* dB = Ls + 8192 + w * 512;      // + buf*12288

  // row stats: M = max of partials, I = 1/(sum+eps)
  if (threadIdx.x < 256) {
    const long long base = ((long long)bz * 2048 + m0 + threadIdx.x) * 16;
    float M = -3.0e38f;
#pragma unroll
    for (int j = 0; j < 16; ++j) M = fmaxf(M, Pm[base + j]);
    float S = 0.f;
#pragma unroll
    for (int j = 0; j < 16; ++j) S += Ps[base + j] * __expf(Pm[base + j] - M);
    rs[threadIdx.x][0] = M;
    rs[threadIdx.x][1] = 1.0f / (S + 1e-6f);
  }
  __syncthreads();
  const int r0 = w * 32 + (lane >> 2);
  const float M0 = rs[r0][0],      I0 = rs[r0][1];
  const float M1 = rs[r0 + 16][0], I1 = rs[r0 + 16][1];

  f32x4 acc[4][4] = {};
  u32x4 gA0, gB0, gA1, gB1;

  // prologue: tiles 0 (gen0/buf0), 1 (gen1/buf1)
  gA0 = gload4(pA);
  gB0 = gload4(pA + ldaB16);
  gload16(pB, dB);
  gA1 = gload4(pA + 64);
  gB1 = gload4(pA + 64 + ldaB16);
  gload16(pB + 64, dB + 12288);
  asm volatile("s_waitcnt vmcnt(3)" ::: "memory");
  __builtin_amdgcn_sched_barrier(0);
  PVSTA(gA0, gB0, dA);
  asm volatile("s_waitcnt vmcnt(0)" ::: "memory");
  __builtin_amdgcn_sched_barrier(0);
  PVSTA(gA1, gB1, dA + 12288);
  asm volatile("s_waitcnt lgkmcnt(0)" ::: "memory");
  __builtin_amdgcn_s_barrier();

  for (int j = 0; j < 32; ++j) {
    const int t0 = 2 * j;
    PVTILE(t0,     0,     12288, gA0, gB0, gA1, gB1);
    PVTILE(t0 + 1, 12288, 0,     gA1, gB1, gA0, gB0);
  }

  // epilogue: f32 out + residual
  const int rB = g4 * 4;
  float* C = Out + (long long)bz * SD;
  const float* Xb = x + (long long)bz * SD;
#pragma unroll
  for (int ni = 0; ni < 4; ++ni) {
    const int col = n0 + wn * 64 + ni * 16 + l15;
#pragma unroll
    for (int mi = 0; mi < 4; ++mi)
#pragma unroll
      for (int r = 0; r < 4; ++r) {
        const int row = m0 + wm * 64 + mi * 16 + rB + r;
        const long long idx = (long long)row * 1024 + col;
        C[idx] = acc[mi][ni][r] + Xb[idx];
      }
  }
}

extern "C" void kernel_launch(void* const* d_in, const int* in_sizes, int n_in,
                              void* d_out, int out_size, void* d_ws, size_t ws_size,
                              hipStream_t stream) {
  const float* x  = (const float*)d_in[0];
  const float* y  = (const float*)d_in[1];
  const float* Wq = (const float*)d_in[2];
  const float* bq = (const float*)d_in[3];
  const float* Wk = (const float*)d_in[4];
  const float* bk = (const float*)d_in[5];
  const float* Wv = (const float*)d_in[6];
  const float* bv = (const float*)d_in[7];
  float* out = (float*)d_out;

  const long long SD  = 2048LL * 1024;
  const long long BSD = 16LL * SD;
  const long long SS  = 2048LL * 2048;

  char* ws = (char*)d_ws;
  short* xb  = (short*)ws;                   // 67.1 MB
  short* yb  = xb + BSD;                     // 67.1 MB
  short* Sl  = (short*)ws;                   // 134.2 MB (aliases xb+yb; written after they die)
  short* Qb  = (short*)(ws + 134217728);     // 67.1 MB
  short* Kb  = Qb + BSD;                     // 67.1 MB
  short* Vt  = Kb + BSD;                     // 67.1 MB  [b][d][s]
  short* Wqt = Vt + BSD;                     // 2 MB each, at byte 335544320
  short* Wkt = Wqt + 1024 * 1024;
  short* Wvt = Wkt + 1024 * 1024;
  // softmax partials overlay the dead Wqt/Wkt region after projections
  float* Pm = (float*)(ws + 335544320);      // [16][2048][16] f32 = 2 MB
  float* Ps = Pm + 524288;                   // 2 MB

  // 1) convert x, y to bf16
  cvt_k<<<2048, 256, 0, stream>>>(x, xb, (int)(BSD / 4));
  cvt_k<<<2048, 256, 0, stream>>>(y, yb, (int)(BSD / 4));

  // 2) transpose+convert weights
  cvtT_k<<<dim3(32, 32), 256, 0, stream>>>(Wq, Wqt);
  cvtT_k<<<dim3(32, 32), 256, 0, stream>>>(Wk, Wkt);
  cvtT_k<<<dim3(32, 32), 256, 0, stream>>>(Wv, Wvt);

  // 3) Q = xb @ Wq + bq
  gemm8_k<0><<<dim3(8, 128, 1), 512, 0, stream>>>(
      xb, Wqt, Qb, bq, 1024, 1024, 1024, 1024, 0, 0, 0, 0, 1.f, nullptr, nullptr);
  // 4) K = yb @ Wk + bk
  gemm8_k<0><<<dim3(8, 128, 1), 512, 0, stream>>>(
      yb, Wkt, Kb, bk, 1024, 1024, 1024, 1024, 0, 0, 0, 0, 1.f, nullptr, nullptr);
  // 5) V^T: A = Wv^T, Bt = yb -> Vt[b][f][s]
  gemm8_k<3><<<dim3(256, 4, 1), 512, 0, stream>>>(
      Wvt, yb, Vt, bv, 1024, 1024, 1024, 0, 0, 0, 0, 0, 1.f, nullptr, nullptr);

  // 6) logits = Q @ K^T / 32 -> Sl raw; also per-row softmax partials Pm/Ps
  gemm8_k<1><<<dim3(16, 8, 16), 512, 0, stream>>>(
      Qb, Kb, Sl, nullptr, 1024, 1024, 1024, 2048, SD, SD, SS, 0, 0.03125f, Pm, Ps);

  // 7) out = softmax(Sl) @ V + x   (fused softmax in A-staging)
  pv_k<<<dim3(8, 8, 16), 512, 0, stream>>>(Sl, Vt, out, x, Pm, Ps);

  (void)in_sizes; (void)n_in; (void)out_size; (void)ws_size;
}

// Round 14
// 799.692 us; speedup vs baseline: 1.8594x; 1.0844x over previous
//
#include <hip/hip_runtime.h>
#include <hip/hip_bf16.h>

typedef __attribute__((ext_vector_type(8))) short bf16x8;
typedef __attribute__((ext_vector_type(4))) float f32x4;
typedef __attribute__((ext_vector_type(4))) unsigned u32x4;

__device__ __forceinline__ float bf2f(short u) {
  union { unsigned int u; float f; } c;
  c.u = ((unsigned int)(unsigned short)u) << 16;
  return c.f;
}
__device__ __forceinline__ short f2bf(float f) {
  union { float f; unsigned int u; } c; c.f = f;
  unsigned int r = (c.u + 0x7fffu + ((c.u >> 16) & 1u)) >> 16;
  return (short)(unsigned short)r;
}

__device__ __forceinline__ void gload16(const void* g, void* l) {
  __builtin_amdgcn_global_load_lds(
      (const __attribute__((address_space(1))) unsigned int*)g,
      (__attribute__((address_space(3))) unsigned int*)l, 16, 0, 0);
}

// scale 2 packed bf16 by f32 factor, repack with RNE via v_cvt_pk_bf16_f32
__device__ __forceinline__ unsigned scale2(unsigned d, float f) {
  union { unsigned u; float x; } lo, hi;
  lo.u = d << 16;
  hi.u = d & 0xffff0000u;
  float a = lo.x * f;
  float b = hi.x * f;
  unsigned out;
  asm("v_cvt_pk_bf16_f32 %0, %1, %2" : "=v"(out) : "v"(a), "v"(b));
  return out;
}

// ---------------- fp32 -> bf16 convert ----------------
__global__ __launch_bounds__(256) void cvt_k(const float* __restrict__ in,
                                             short* __restrict__ out, int n4) {
  int i = blockIdx.x * blockDim.x + threadIdx.x;
  const int stride = gridDim.x * blockDim.x;
  for (; i < n4; i += stride) {
    float4 v = ((const float4*)in)[i];
    short4 o;
    o.x = f2bf(v.x); o.y = f2bf(v.y); o.z = f2bf(v.z); o.w = f2bf(v.w);
    ((short4*)out)[i] = o;
  }
}

// ---------------- W [1024][1024] f32 -> W^T bf16 ----------------
__global__ __launch_bounds__(256) void cvtT_k(const float* __restrict__ W,
                                              short* __restrict__ Wt) {
  __shared__ float tile[32][33];
  const int n0 = blockIdx.x * 32, k0 = blockIdx.y * 32;
  const int tr = threadIdx.x >> 5;
  const int tc = threadIdx.x & 31;
#pragma unroll
  for (int p = 0; p < 4; ++p)
    tile[p * 8 + tr][tc] = W[(long long)(k0 + p * 8 + tr) * 1024 + n0 + tc];
  __syncthreads();
#pragma unroll
  for (int p = 0; p < 4; ++p)
    Wt[(long long)(n0 + p * 8 + tr) * 1024 + k0 + tc] = f2bf(tile[tc][p * 8 + tr]);
}

// =====================================================================
// gemm256_k: 256x256x64 8-phase bf16 MFMA GEMM (R6 core, validated)
// for projections (EPI 0: bf16 +bias[col]) and V^T (EPI 3).
// =====================================================================

#define STG6(sp, ld8, dOff) do { \
  gload16((sp), Ls + (dOff)); \
  gload16((const char*)(sp) + (ld8), Ls + (dOff) + 512); } while (0)

#define RD_A6(BUF, QM) do { \
  _Pragma("unroll") \
  for (int mi = 0; mi < 4; ++mi) { \
    aR[mi][0] = *(const bf16x8*)(Ls + (BUF) + (QM)*8192 + arow + mi*1024 + aO0); \
    aR[mi][1] = *(const bf16x8*)(Ls + (BUF) + (QM)*8192 + arow + mi*1024 + aO1); \
  } } while (0)

#define RD_B6(DST, BUF, QN) do { \
  _Pragma("unroll") \
  for (int ni = 0; ni < 2; ++ni) { \
    DST[ni][0] = *(const bf16x8*)(Ls + (BUF) + 16384 + (QN)*8192 + brow + ni*1024 + aO0); \
    DST[ni][1] = *(const bf16x8*)(Ls + (BUF) + 16384 + (QN)*8192 + brow + ni*1024 + aO1); \
  } } while (0)

#define SYNCIN6 do { \
  __builtin_amdgcn_sched_barrier(0); \
  __builtin_amdgcn_s_barrier(); \
  asm volatile("s_waitcnt lgkmcnt(0)" ::: "memory"); \
  __builtin_amdgcn_sched_barrier(0); \
  __builtin_amdgcn_s_setprio(1); } while (0)

#define SYNCOUT6 do { \
  __builtin_amdgcn_s_setprio(0); \
  __builtin_amdgcn_s_barrier(); } while (0)

#define MF166(ACCQ, BB) do { \
  _Pragma("unroll") \
  for (int mi = 0; mi < 4; ++mi) { \
    _Pragma("unroll") \
    for (int ni = 0; ni < 2; ++ni) { \
      ACCQ[mi][ni] = __builtin_amdgcn_mfma_f32_16x16x32_bf16(aR[mi][0], BB[ni][0], ACCQ[mi][ni], 0, 0, 0); \
      ACCQ[mi][ni] = __builtin_amdgcn_mfma_f32_16x16x32_bf16(aR[mi][1], BB[ni][1], ACCQ[mi][ni], 0, 0, 0); \
    } \
  } } while (0)

template<int EPI>
__global__ __launch_bounds__(512) void gemm256_k(
    const short* __restrict__ A, const short* __restrict__ Bt,
    void* __restrict__ Cv, const float* __restrict__ X,
    int K, int lda, int ldb, int ldc) {
  __shared__ __align__(16) short Ls[65536];   // 128 KiB

  const int lane = threadIdx.x & 63;
  const int w = threadIdx.x >> 6;
  const int wm = w >> 2, wn = w & 3;
  const int w1k = w * 1024;
  const int l15 = lane & 15;
  const int g4 = lane >> 4;
  const int p8 = lane & 7;
  const int r8 = lane >> 3;
  const int aO0 = (g4 ^ p8) << 3;
  const int aO1 = ((4 + g4) ^ p8) << 3;
  const int arow = (wm * 64 + l15) * 64;
  const int brow = (wn * 32 + l15) * 64;

  const int gx = gridDim.x, gy = gridDim.y;
  const int nwg = gx * gy * gridDim.z;
  int lid = blockIdx.x + gx * (blockIdx.y + gy * blockIdx.z);
  lid = (lid & 7) * (nwg >> 3) + (lid >> 3);
  const int bx = lid % gx;
  const int rem = lid / gx;
  const int by = rem % gy;
  const int bz = rem / gy;

  const int n0 = bx * 256;
  const int m0 = by * 256;
  const int nt = K >> 6;
  const int nit = nt >> 1;

  const long long ldaB = 2LL * lda, ldbB = 2LL * ldb;
  const long long ldaB8 = 8 * ldaB, ldbB8 = 8 * ldbB;
  const long long hOffA = 128 * ldaB, hOffB = 128 * ldbB;

  const char* pA = (const char*)A
      + (long long)(m0 + w * 16 + r8) * ldaB + ((p8 ^ r8) << 4);
  const char* pB = (const char*)Bt
      + (long long)(n0 + w * 16 + r8) * ldbB + ((p8 ^ r8) << 4);
  (void)bz;

  f32x4 acc[2][2][4][2] = {};
  bf16x8 aR[4][2], bR0[2][2], bR1[2][2];

  STG6(pA,                 ldaB8, 0 + w1k);
  STG6(pA + hOffA,         ldaB8, 8192 + w1k);
  STG6(pB,                 ldbB8, 16384 + w1k);
  STG6(pB + hOffB,         ldbB8, 24576 + w1k);
  STG6(pA + 128,           ldaB8, 32768 + w1k);
  STG6(pA + 128 + hOffA,   ldaB8, 40960 + w1k);
  STG6(pB + 128,           ldbB8, 49152 + w1k);
  STG6(pB + 128 + hOffB,   ldbB8, 57344 + w1k);
  asm volatile("s_waitcnt vmcnt(8)" ::: "memory");
  __builtin_amdgcn_s_barrier();

  for (int j = 0; j < nit; ++j) {
    const bool st = (j + 1 < nit);

    RD_A6(0, 0); RD_B6(bR0, 0, 0);
    SYNCIN6; MF166(acc[0][0], bR0); SYNCOUT6;
    RD_B6(bR1, 0, 1);
    if (st) { STG6(pA + 256, ldaB8, 0 + w1k);
              STG6(pB + 256, ldbB8, 16384 + w1k); }
    SYNCIN6; MF166(acc[0][1], bR1); SYNCOUT6;
    RD_A6(0, 1);
    if (st) STG6(pB + 256 + hOffB, ldbB8, 24576 + w1k);
    SYNCIN6; MF166(acc[1][1], bR1); SYNCOUT6;
    if (st) STG6(pA + 256 + hOffA, ldaB8, 8192 + w1k);
    SYNCIN6; MF166(acc[1][0], bR0);
    __builtin_amdgcn_s_setprio(0);
    if (st) asm volatile("s_waitcnt vmcnt(8)" ::: "memory");
    else    asm volatile("s_waitcnt vmcnt(0)" ::: "memory");
    __builtin_amdgcn_s_barrier();

    RD_A6(32768, 0); RD_B6(bR0, 32768, 0);
    SYNCIN6; MF166(acc[0][0], bR0); SYNCOUT6;
    RD_B6(bR1, 32768, 1);
    if (st) { STG6(pA + 384, ldaB8, 32768 + w1k);
              STG6(pB + 384, ldbB8, 49152 + w1k); }
    SYNCIN6; MF166(acc[0][1], bR1); SYNCOUT6;
    RD_A6(32768, 1);
    if (st) STG6(pB + 384 + hOffB, ldbB8, 57344 + w1k);
    SYNCIN6; MF166(acc[1][1], bR1); SYNCOUT6;
    if (st) STG6(pA + 384 + hOffA, ldaB8, 40960 + w1k);
    SYNCIN6; MF166(acc[1][0], bR0);
    __builtin_amdgcn_s_setprio(0);
    if (st) asm volatile("s_waitcnt vmcnt(8)" ::: "memory");
    __builtin_amdgcn_s_barrier();

    pA += 256; pB += 256;
  }

  const int rB = g4 * 4;
  if (EPI == 0) {
    short* C = (short*)Cv;
#pragma unroll
    for (int qn = 0; qn < 2; ++qn)
#pragma unroll
      for (int ni = 0; ni < 2; ++ni) {
        const int col = n0 + qn * 128 + wn * 32 + ni * 16 + l15;
        const float bv = X[col];
#pragma unroll
        for (int qm = 0; qm < 2; ++qm)
#pragma unroll
          for (int mi = 0; mi < 4; ++mi)
#pragma unroll
            for (int r = 0; r < 4; ++r) {
              const int row = m0 + qm * 128 + wm * 64 + mi * 16 + rB + r;
              C[(long long)row * ldc + col] = f2bf(acc[qm][qn][mi][ni][r] + bv);
            }
      }
  } else {  // EPI == 3: C = V^T, [b][f=row][s], n = b*2048 + s
    short* C = (short*)Cv;
#pragma unroll
    for (int qn = 0; qn < 2; ++qn)
#pragma unroll
      for (int ni = 0; ni < 2; ++ni) {
        const int col = n0 + qn * 128 + wn * 32 + ni * 16 + l15;
        const int b2 = col >> 11;
        const int s = col & 2047;
#pragma unroll
        for (int qm = 0; qm < 2; ++qm)
#pragma unroll
          for (int mi = 0; mi < 4; ++mi)
#pragma unroll
            for (int r = 0; r < 4; ++r) {
              const int row = m0 + qm * 128 + wm * 64 + mi * 16 + rB + r;
              C[(long long)b2 * 2097152 + (long long)row * 2048 + s] =
                  f2bf(acc[qm][qn][mi][ni][r] + X[row]);
            }
      }
  }
}

// =====================================================================
// gemmQK_k: 256x128x32 triple-buffered (R8 core) QK^T.
// Epilogue: per-row block partials (m, sum_exp) -> Pm/Ps, and stores
// P~ = exp(v - m_block) as bf16 into Sl.
// =====================================================================

__global__ __launch_bounds__(512, 4) void gemmQK_k(
    const short* __restrict__ A, const short* __restrict__ Bt,
    short* __restrict__ Cv,
    int K, int lda, int ldb, int ldc,
    long long strA, long long strB, long long strC, float scale,
    float* __restrict__ Pm, float* __restrict__ Ps) {
  __shared__ __align__(16) short Ls[36864];   // 72 KiB

  const int lane = threadIdx.x & 63;
  const int w = threadIdx.x >> 6;
  const int wm = w >> 1, wn = w & 1;
  const int l15 = lane & 15;
  const int g4 = lane >> 4;
  const int swR = ((g4 ^ ((l15 >> 1) & 3)) << 3);
  const int arow = (wm * 64 + l15) * 32 + swR;
  const int brow = (wn * 64 + l15) * 32 + swR;
  const int sg = (lane & 3) ^ ((lane >> 3) & 3);

  const int gx = gridDim.x, gy = gridDim.y;
  const int nwg = gx * gy * gridDim.z;
  int lid = blockIdx.x + gx * (blockIdx.y + gy * blockIdx.z);
  lid = (lid & 7) * (nwg >> 3) + (lid >> 3);
  const int bx = lid % gx;
  const int rem = lid / gx;
  const int by = rem % gy;
  const int bz = rem / gy;

  const int n0 = bx * 128;
  const int m0 = by * 256;
  const int nt = K >> 5;

  const long long ldaB = 2LL * lda, ldbB = 2LL * ldb;
  const long long ldaB16 = 16 * ldaB;

  const char* pA = (const char*)(A + (long long)bz * strA)
      + (long long)(m0 + w * 32 + (lane >> 2)) * ldaB + sg * 16;
  const char* pB = (const char*)(Bt + (long long)bz * strB)
      + (long long)(n0 + w * 16 + (lane >> 2)) * ldbB + sg * 16;

  short* dA = Ls + w * 1024;
  short* dB = Ls + 8192 + w * 512;

  f32x4 acc[4][4] = {};

#pragma unroll
  for (int i = 0; i < 3; ++i) {
    const char* qA = pA + i * 64;
    gload16(qA,           dA + i * 12288);
    gload16(qA + ldaB16,  dA + i * 12288 + 512);
    gload16(pB + i * 64,  dB + i * 12288);
  }
  asm volatile("s_waitcnt vmcnt(6)" ::: "memory");
  __builtin_amdgcn_s_barrier();

  int cur = 0;
  for (int t = 0; t < nt; ++t) {
    const int bufO = cur * 12288;
    bf16x8 aR[4], bR[4];
#pragma unroll
    for (int mi = 0; mi < 4; ++mi)
      aR[mi] = *(const bf16x8*)(Ls + bufO + arow + mi * 512);
#pragma unroll
    for (int ni = 0; ni < 4; ++ni)
      bR[ni] = *(const bf16x8*)(Ls + bufO + 8192 + brow + ni * 512);
    asm volatile("s_waitcnt lgkmcnt(0)" ::: "memory");
    __builtin_amdgcn_s_barrier();
    if (t + 3 < nt) {
      const char* qA = pA + (t + 3) * 64;
      gload16(qA,          dA + bufO);
      gload16(qA + ldaB16, dA + bufO + 512);
      gload16(pB + (t + 3) * 64, dB + bufO);
    }
    __builtin_amdgcn_sched_barrier(0);
    __builtin_amdgcn_s_setprio(1);
#pragma unroll
    for (int mi = 0; mi < 4; ++mi)
#pragma unroll
      for (int ni = 0; ni < 4; ++ni)
        acc[mi][ni] = __builtin_amdgcn_mfma_f32_16x16x32_bf16(
            aR[mi], bR[ni], acc[mi][ni], 0, 0, 0);
    __builtin_amdgcn_s_setprio(0);
    if (t + 3 < nt)      asm volatile("s_waitcnt vmcnt(6)" ::: "memory");
    else if (t + 2 < nt) asm volatile("s_waitcnt vmcnt(3)" ::: "memory");
    else                 asm volatile("s_waitcnt vmcnt(0)" ::: "memory");
    __builtin_amdgcn_s_barrier();
    cur = (cur == 2) ? 0 : cur + 1;
  }

  // ---- epilogue: partials + P~ write ----
  const int rB = g4 * 4;
  short* C = Cv + (long long)bz * strC;
  float mA[16], sA_[16];
#pragma unroll
  for (int mi = 0; mi < 4; ++mi)
#pragma unroll
    for (int r = 0; r < 4; ++r) {
      const int ix = mi * 4 + r;
      float v0 = acc[mi][0][r] * scale, v1 = acc[mi][1][r] * scale;
      float v2 = acc[mi][2][r] * scale, v3 = acc[mi][3][r] * scale;
      float m = fmaxf(fmaxf(v0, v1), fmaxf(v2, v3));
      float s = __expf(v0 - m) + __expf(v1 - m) + __expf(v2 - m) + __expf(v3 - m);
#pragma unroll
      for (int o = 1; o < 16; o <<= 1) {
        float mo = __shfl_xor(m, o), so = __shfl_xor(s, o);
        float M = fmaxf(m, mo);
        s = s * __expf(m - M) + so * __expf(mo - M);
        m = M;
      }
      mA[ix] = m; sA_[ix] = s;
    }
  float* lm = (float*)Ls;     // [256]
  float* ls2 = lm + 256;      // [256]
  __syncthreads();
  if (wn == 1 && l15 == 0) {
#pragma unroll
    for (int mi = 0; mi < 4; ++mi)
#pragma unroll
      for (int r = 0; r < 4; ++r) {
        const int lr = wm * 64 + mi * 16 + rB + r;
        lm[lr] = mA[mi * 4 + r]; ls2[lr] = sA_[mi * 4 + r];
      }
  }
  __syncthreads();
  if (wn == 0 && l15 == 0) {
#pragma unroll
    for (int mi = 0; mi < 4; ++mi)
#pragma unroll
      for (int r = 0; r < 4; ++r) {
        const int lr = wm * 64 + mi * 16 + rB + r;
        float m1 = mA[mi * 4 + r], s1 = sA_[mi * 4 + r];
        float m2 = lm[lr], s2 = ls2[lr];
        float M = fmaxf(m1, m2);
        float S = s1 * __expf(m1 - M) + s2 * __expf(m2 - M);
        const long long pidx = ((long long)bz * 2048 + m0 + lr) * 16 + bx;
        Pm[pidx] = M; Ps[pidx] = S;
        lm[lr] = M;              // publish final block max
      }
  }
  __syncthreads();
#pragma unroll
  for (int ni = 0; ni < 4; ++ni) {
    const int col = n0 + wn * 64 + ni * 16 + l15;
#pragma unroll
    for (int mi = 0; mi < 4; ++mi)
#pragma unroll
      for (int r = 0; r < 4; ++r) {
        const int lr = wm * 64 + mi * 16 + rB + r;
        const float mF = lm[lr];
        const int row = m0 + lr;
        C[(long long)row * ldc + col] = f2bf(__expf(acc[mi][ni][r] * scale - mF));
      }
  }
}

// =====================================================================
// pv_k: out = softmax @ V + x.  A = P~ (bf16, e^{v-m_b}), staged via
// gload_lds; per-fragment rescale by fac[b][row] = e^{m_b - M}/(S+eps).
// Double-buffered 48KB + 16KB fac -> 2 blocks/CU.
// =====================================================================

__global__ __launch_bounds__(512, 4) void pv_k(
    const short* __restrict__ Sl, const short* __restrict__ Vt,
    float* __restrict__ Out, const float* __restrict__ x,
    const float* __restrict__ Pm, const float* __restrict__ Ps) {
  __shared__ __align__(16) short Ls[24576];   // 48KB: 2 bufs x (A 8192 + B 4096)
  __shared__ float fac[16][256];              // 16KB

  const int lane = threadIdx.x & 63;
  const int w = threadIdx.x >> 6;
  const int wm = w >> 1, wn = w & 1;
  const int l15 = lane & 15;
  const int g4 = lane >> 4;
  const int swR = ((g4 ^ ((l15 >> 1) & 3)) << 3);
  const int arow = (wm * 64 + l15) * 32 + swR;
  const int brow = (wn * 64 + l15) * 32 + swR;
  const int sg = (lane & 3) ^ ((lane >> 3) & 3);

  const int nwg = 1024;                 // grid (8,8,16)
  int lid = blockIdx.x + 8 * (blockIdx.y + 8 * blockIdx.z);
  lid = (lid & 7) * (nwg >> 3) + (lid >> 3);
  const int bx = lid % 8;
  const int rem = lid / 8;
  const int by = rem % 8;
  const int bz = rem / 8;
  const int n0 = bx * 128, m0 = by * 256;
  const int nt = 64;                    // K = 2048, BK = 32

  const long long SS = 4194304LL, SD = 2097152LL;
  const long long ldaB = 4096, ldbB = 4096;
  const long long ldaB16 = 16 * ldaB;

  const char* pA = (const char*)(Sl + (long long)bz * SS)
      + (long long)(m0 + w * 32 + (lane >> 2)) * ldaB + sg * 16;
  const char* pB = (const char*)(Vt + (long long)bz * SD)
      + (long long)(n0 + w * 16 + (lane >> 2)) * ldbB + sg * 16;

  short* dA = Ls + w * 1024;            // + buf*12288
  short* dB = Ls + 8192 + w * 512;      // + buf*12288

  // fac table: fac[b][r] = exp(Pm[r][b] - M[r]) / (S[r] + eps)
  if (threadIdx.x < 256) {
    const long long base = ((long long)bz * 2048 + m0 + threadIdx.x) * 16;
    float M = -3.0e38f;
#pragma unroll
    for (int j = 0; j < 16; ++j) M = fmaxf(M, Pm[base + j]);
    float S = 0.f;
#pragma unroll
    for (int j = 0; j < 16; ++j) S += Ps[base + j] * __expf(Pm[base + j] - M);
    const float I = 1.0f / (S + 1e-6f);
#pragma unroll
    for (int j = 0; j < 16; ++j)
      fac[j][threadIdx.x] = __expf(Pm[base + j] - M) * I;
  }
  __syncthreads();

  f32x4 acc[4][4] = {};

  // prologue: stage tiles 0 -> buf0, 1 -> buf1
  gload16(pA,               dA);
  gload16(pA + ldaB16,      dA + 512);
  gload16(pB,               dB);
  gload16(pA + 64,          dA + 12288);
  gload16(pA + 64 + ldaB16, dA + 12288 + 512);
  gload16(pB + 64,          dB + 12288);
  asm volatile("s_waitcnt vmcnt(3)" ::: "memory");
  __builtin_amdgcn_s_barrier();

  for (int t = 0; t < nt; ++t) {
    const int bufO = (t & 1) * 12288;
    bf16x8 aR[4], bR[4];
#pragma unroll
    for (int mi = 0; mi < 4; ++mi)
      aR[mi] = *(const bf16x8*)(Ls + bufO + arow + mi * 512);
#pragma unroll
    for (int ni = 0; ni < 4; ++ni)
      bR[ni] = *(const bf16x8*)(Ls + bufO + 8192 + brow + ni * 512);
    asm volatile("s_waitcnt lgkmcnt(0)" ::: "memory");
    __builtin_amdgcn_s_barrier();
    if (t + 2 < nt) {
      const char* qA = pA + (t + 2) * 64;
      gload16(qA,          dA + bufO);
      gload16(qA + ldaB16, dA + bufO + 512);
      gload16(pB + (t + 2) * 64, dB + bufO);
    }
    __builtin_amdgcn_sched_barrier(0);
    // rescale A-fragments: one factor per (row, source block)
    const int b = t >> 2;
#pragma unroll
    for (int mi = 0; mi < 4; ++mi) {
      const float fv = fac[b][wm * 64 + mi * 16 + l15];
      u32x4 d = __builtin_bit_cast(u32x4, aR[mi]);
      d[0] = scale2(d[0], fv);
      d[1] = scale2(d[1], fv);
      d[2] = scale2(d[2], fv);
      d[3] = scale2(d[3], fv);
      aR[mi] = __builtin_bit_cast(bf16x8, d);
    }
    __builtin_amdgcn_s_setprio(1);
#pragma unroll
    for (int mi = 0; mi < 4; ++mi)
#pragma unroll
      for (int ni = 0; ni < 4; ++ni)
        acc[mi][ni] = __builtin_amdgcn_mfma_f32_16x16x32_bf16(
            aR[mi], bR[ni], acc[mi][ni], 0, 0, 0);
    __builtin_amdgcn_s_setprio(0);
    if (t + 2 < nt) asm volatile("s_waitcnt vmcnt(3)" ::: "memory");
    else            asm volatile("s_waitcnt vmcnt(0)" ::: "memory");
    __builtin_amdgcn_s_barrier();
  }

  // epilogue: f32 out + residual
  const int rB = g4 * 4;
  float* C = Out + (long long)bz * SD;
  const float* Xb = x + (long long)bz * SD;
#pragma unroll
  for (int ni = 0; ni < 4; ++ni) {
    const int col = n0 + wn * 64 + ni * 16 + l15;
#pragma unroll
    for (int mi = 0; mi < 4; ++mi)
#pragma unroll
      for (int r = 0; r < 4; ++r) {
        const int row = m0 + wm * 64 + mi * 16 + rB + r;
        const long long idx = (long long)row * 1024 + col;
        C[idx] = acc[mi][ni][r] + Xb[idx];
      }
  }
}

extern "C" void kernel_launch(void* const* d_in, const int* in_sizes, int n_in,
                              void* d_out, int out_size, void* d_ws, size_t ws_size,
                              hipStream_t stream) {
  const float* x  = (const float*)d_in[0];
  const float* y  = (const float*)d_in[1];
  const float* Wq = (const float*)d_in[2];
  const float* bq = (const float*)d_in[3];
  const float* Wk = (const float*)d_in[4];
  const float* bk = (const float*)d_in[5];
  const float* Wv = (const float*)d_in[6];
  const float* bv = (const float*)d_in[7];
  float* out = (float*)d_out;

  const long long SD  = 2048LL * 1024;
  const long long BSD = 16LL * SD;
  const long long SS  = 2048LL * 2048;

  char* ws = (char*)d_ws;
  short* xb  = (short*)ws;                   // 67.1 MB
  short* yb  = xb + BSD;                     // 67.1 MB
  short* Sl  = (short*)ws;                   // 134.2 MB (aliases xb+yb; written after they die)
  short* Qb  = (short*)(ws + 134217728);     // 67.1 MB
  short* Kb  = Qb + BSD;                     // 67.1 MB
  short* Vt  = Kb + BSD;                     // 67.1 MB  [b][d][s]
  short* Wqt = Vt + BSD;                     // 2 MB each, at byte 335544320
  short* Wkt = Wqt + 1024 * 1024;
  short* Wvt = Wkt + 1024 * 1024;
  // softmax partials overlay the dead Wqt/Wkt region after projections
  float* Pm = (float*)(ws + 335544320);      // [16][2048][16] f32 = 2 MB
  float* Ps = Pm + 524288;                   // 2 MB

  // 1) convert x, y to bf16
  cvt_k<<<2048, 256, 0, stream>>>(x, xb, (int)(BSD / 4));
  cvt_k<<<2048, 256, 0, stream>>>(y, yb, (int)(BSD / 4));

  // 2) transpose+convert weights
  cvtT_k<<<dim3(32, 32), 256, 0, stream>>>(Wq, Wqt);
  cvtT_k<<<dim3(32, 32), 256, 0, stream>>>(Wk, Wkt);
  cvtT_k<<<dim3(32, 32), 256, 0, stream>>>(Wv, Wvt);

  // 3) Q = xb @ Wq + bq  (256^2 8-phase kernel)
  gemm256_k<0><<<dim3(4, 128, 1), 512, 0, stream>>>(
      xb, Wqt, Qb, bq, 1024, 1024, 1024, 1024);
  // 4) K = yb @ Wk + bk
  gemm256_k<0><<<dim3(4, 128, 1), 512, 0, stream>>>(
      yb, Wkt, Kb, bk, 1024, 1024, 1024, 1024);
  // 5) V^T: A = Wv^T, Bt = yb -> Vt[b][f][s]
  gemm256_k<3><<<dim3(128, 4, 1), 512, 0, stream>>>(
      Wvt, yb, Vt, bv, 1024, 1024, 1024, 0);

  // 6) QK^T -> Sl = P~ = exp(v - m_block), partials Pm/Ps
  gemmQK_k<<<dim3(16, 8, 16), 512, 0, stream>>>(
      Qb, Kb, Sl, 1024, 1024, 1024, 2048, SD, SD, SS, 0.03125f, Pm, Ps);

  // 7) out = (P~ * fac) @ V + x
  pv_k<<<dim3(8, 8, 16), 512, 0, stream>>>(Sl, Vt, out, x, Pm, Ps);

  (void)in_sizes; (void)n_in; (void)out_size; (void)ws_size;
}

// Round 15
// 739.324 us; speedup vs baseline: 2.0112x; 1.0817x over previous
//
#include <hip/hip_runtime.h>
#include <hip/hip_bf16.h>

typedef __attribute__((ext_vector_type(8))) short bf16x8;
typedef __attribute__((ext_vector_type(4))) float f32x4;

__device__ __forceinline__ float bf2f(short u) {
  union { unsigned int u; float f; } c;
  c.u = ((unsigned int)(unsigned short)u) << 16;
  return c.f;
}
__device__ __forceinline__ short f2bf(float f) {
  union { float f; unsigned int u; } c; c.f = f;
  unsigned int r = (c.u + 0x7fffu + ((c.u >> 16) & 1u)) >> 16;
  return (short)(unsigned short)r;
}

__device__ __forceinline__ void gload16(const void* g, void* l) {
  __builtin_amdgcn_global_load_lds(
      (const __attribute__((address_space(1))) unsigned int*)g,
      (__attribute__((address_space(3))) unsigned int*)l, 16, 0, 0);
}

// ---------------- fp32 -> bf16 convert ----------------
__global__ __launch_bounds__(256) void cvt_k(const float* __restrict__ in,
                                             short* __restrict__ out, int n4) {
  int i = blockIdx.x * blockDim.x + threadIdx.x;
  const int stride = gridDim.x * blockDim.x;
  for (; i < n4; i += stride) {
    float4 v = ((const float4*)in)[i];
    short4 o;
    o.x = f2bf(v.x); o.y = f2bf(v.y); o.z = f2bf(v.z); o.w = f2bf(v.w);
    ((short4*)out)[i] = o;
  }
}

// ---------------- W [1024][1024] f32 -> W^T bf16 ----------------
__global__ __launch_bounds__(256) void cvtT_k(const float* __restrict__ W,
                                              short* __restrict__ Wt) {
  __shared__ float tile[32][33];
  const int n0 = blockIdx.x * 32, k0 = blockIdx.y * 32;
  const int tr = threadIdx.x >> 5;
  const int tc = threadIdx.x & 31;
#pragma unroll
  for (int p = 0; p < 4; ++p)
    tile[p * 8 + tr][tc] = W[(long long)(k0 + p * 8 + tr) * 1024 + n0 + tc];
  __syncthreads();
#pragma unroll
  for (int p = 0; p < 4; ++p)
    Wt[(long long)(n0 + p * 8 + tr) * 1024 + k0 + tc] = f2bf(tile[tc][p * 8 + tr]);
}

// =====================================================================
// gemm256_k: 256x256x64 8-phase bf16 MFMA GEMM (R6 core, validated)
// for projections (EPI 0: bf16 +bias[col]) and V^T (EPI 3).
// =====================================================================

#define STG6(sp, ld8, dOff) do { \
  gload16((sp), Ls + (dOff)); \
  gload16((const char*)(sp) + (ld8), Ls + (dOff) + 512); } while (0)

#define RD_A6(BUF, QM) do { \
  _Pragma("unroll") \
  for (int mi = 0; mi < 4; ++mi) { \
    aR[mi][0] = *(const bf16x8*)(Ls + (BUF) + (QM)*8192 + arow + mi*1024 + aO0); \
    aR[mi][1] = *(const bf16x8*)(Ls + (BUF) + (QM)*8192 + arow + mi*1024 + aO1); \
  } } while (0)

#define RD_B6(DST, BUF, QN) do { \
  _Pragma("unroll") \
  for (int ni = 0; ni < 2; ++ni) { \
    DST[ni][0] = *(const bf16x8*)(Ls + (BUF) + 16384 + (QN)*8192 + brow + ni*1024 + aO0); \
    DST[ni][1] = *(const bf16x8*)(Ls + (BUF) + 16384 + (QN)*8192 + brow + ni*1024 + aO1); \
  } } while (0)

#define SYNCIN6 do { \
  __builtin_amdgcn_sched_barrier(0); \
  __builtin_amdgcn_s_barrier(); \
  asm volatile("s_waitcnt lgkmcnt(0)" ::: "memory"); \
  __builtin_amdgcn_sched_barrier(0); \
  __builtin_amdgcn_s_setprio(1); } while (0)

#define SYNCOUT6 do { \
  __builtin_amdgcn_s_setprio(0); \
  __builtin_amdgcn_s_barrier(); } while (0)

#define MF166(ACCQ, BB) do { \
  _Pragma("unroll") \
  for (int mi = 0; mi < 4; ++mi) { \
    _Pragma("unroll") \
    for (int ni = 0; ni < 2; ++ni) { \
      ACCQ[mi][ni] = __builtin_amdgcn_mfma_f32_16x16x32_bf16(aR[mi][0], BB[ni][0], ACCQ[mi][ni], 0, 0, 0); \
      ACCQ[mi][ni] = __builtin_amdgcn_mfma_f32_16x16x32_bf16(aR[mi][1], BB[ni][1], ACCQ[mi][ni], 0, 0, 0); \
    } \
  } } while (0)

template<int EPI>
__global__ __launch_bounds__(512) void gemm256_k(
    const short* __restrict__ A, const short* __restrict__ Bt,
    void* __restrict__ Cv, const float* __restrict__ X,
    int K, int lda, int ldb, int ldc) {
  __shared__ __align__(16) short Ls[65536];   // 128 KiB

  const int lane = threadIdx.x & 63;
  const int w = threadIdx.x >> 6;
  const int wm = w >> 2, wn = w & 3;
  const int w1k = w * 1024;
  const int l15 = lane & 15;
  const int g4 = lane >> 4;
  const int p8 = lane & 7;
  const int r8 = lane >> 3;
  const int aO0 = (g4 ^ p8) << 3;
  const int aO1 = ((4 + g4) ^ p8) << 3;
  const int arow = (wm * 64 + l15) * 64;
  const int brow = (wn * 32 + l15) * 64;

  const int gx = gridDim.x, gy = gridDim.y;
  const int nwg = gx * gy * gridDim.z;
  int lid = blockIdx.x + gx * (blockIdx.y + gy * blockIdx.z);
  lid = (lid & 7) * (nwg >> 3) + (lid >> 3);
  const int bx = lid % gx;
  const int rem = lid / gx;
  const int by = rem % gy;

  const int n0 = bx * 256;
  const int m0 = by * 256;
  const int nt = K >> 6;
  const int nit = nt >> 1;

  const long long ldaB = 2LL * lda, ldbB = 2LL * ldb;
  const long long ldaB8 = 8 * ldaB, ldbB8 = 8 * ldbB;
  const long long hOffA = 128 * ldaB, hOffB = 128 * ldbB;

  const char* pA = (const char*)A
      + (long long)(m0 + w * 16 + r8) * ldaB + ((p8 ^ r8) << 4);
  const char* pB = (const char*)Bt
      + (long long)(n0 + w * 16 + r8) * ldbB + ((p8 ^ r8) << 4);

  f32x4 acc[2][2][4][2] = {};
  bf16x8 aR[4][2], bR0[2][2], bR1[2][2];

  STG6(pA,                 ldaB8, 0 + w1k);
  STG6(pA + hOffA,         ldaB8, 8192 + w1k);
  STG6(pB,                 ldbB8, 16384 + w1k);
  STG6(pB + hOffB,         ldbB8, 24576 + w1k);
  STG6(pA + 128,           ldaB8, 32768 + w1k);
  STG6(pA + 128 + hOffA,   ldaB8, 40960 + w1k);
  STG6(pB + 128,           ldbB8, 49152 + w1k);
  STG6(pB + 128 + hOffB,   ldbB8, 57344 + w1k);
  asm volatile("s_waitcnt vmcnt(8)" ::: "memory");
  __builtin_amdgcn_s_barrier();

  for (int j = 0; j < nit; ++j) {
    const bool st = (j + 1 < nit);

    RD_A6(0, 0); RD_B6(bR0, 0, 0);
    SYNCIN6; MF166(acc[0][0], bR0); SYNCOUT6;
    RD_B6(bR1, 0, 1);
    if (st) { STG6(pA + 256, ldaB8, 0 + w1k);
              STG6(pB + 256, ldbB8, 16384 + w1k); }
    SYNCIN6; MF166(acc[0][1], bR1); SYNCOUT6;
    RD_A6(0, 1);
    if (st) STG6(pB + 256 + hOffB, ldbB8, 24576 + w1k);
    SYNCIN6; MF166(acc[1][1], bR1); SYNCOUT6;
    if (st) STG6(pA + 256 + hOffA, ldaB8, 8192 + w1k);
    SYNCIN6; MF166(acc[1][0], bR0);
    __builtin_amdgcn_s_setprio(0);
    if (st) asm volatile("s_waitcnt vmcnt(8)" ::: "memory");
    else    asm volatile("s_waitcnt vmcnt(0)" ::: "memory");
    __builtin_amdgcn_s_barrier();

    RD_A6(32768, 0); RD_B6(bR0, 32768, 0);
    SYNCIN6; MF166(acc[0][0], bR0); SYNCOUT6;
    RD_B6(bR1, 32768, 1);
    if (st) { STG6(pA + 384, ldaB8, 32768 + w1k);
              STG6(pB + 384, ldbB8, 49152 + w1k); }
    SYNCIN6; MF166(acc[0][1], bR1); SYNCOUT6;
    RD_A6(32768, 1);
    if (st) STG6(pB + 384 + hOffB, ldbB8, 57344 + w1k);
    SYNCIN6; MF166(acc[1][1], bR1); SYNCOUT6;
    if (st) STG6(pA + 384 + hOffA, ldaB8, 40960 + w1k);
    SYNCIN6; MF166(acc[1][0], bR0);
    __builtin_amdgcn_s_setprio(0);
    if (st) asm volatile("s_waitcnt vmcnt(8)" ::: "memory");
    __builtin_amdgcn_s_barrier();

    pA += 256; pB += 256;
  }

  const int rB = g4 * 4;
  if (EPI == 0) {
    short* C = (short*)Cv;
#pragma unroll
    for (int qn = 0; qn < 2; ++qn)
#pragma unroll
      for (int ni = 0; ni < 2; ++ni) {
        const int col = n0 + qn * 128 + wn * 32 + ni * 16 + l15;
        const float bv = X[col];
#pragma unroll
        for (int qm = 0; qm < 2; ++qm)
#pragma unroll
          for (int mi = 0; mi < 4; ++mi)
#pragma unroll
            for (int r = 0; r < 4; ++r) {
              const int row = m0 + qm * 128 + wm * 64 + mi * 16 + rB + r;
              C[(long long)row * ldc + col] = f2bf(acc[qm][qn][mi][ni][r] + bv);
            }
      }
  } else {  // EPI == 3: C = V^T, [b][f=row][s], n = b*2048 + s
    short* C = (short*)Cv;
#pragma unroll
    for (int qn = 0; qn < 2; ++qn)
#pragma unroll
      for (int ni = 0; ni < 2; ++ni) {
        const int col = n0 + qn * 128 + wn * 32 + ni * 16 + l15;
        const int b2 = col >> 11;
        const int s = col & 2047;
#pragma unroll
        for (int qm = 0; qm < 2; ++qm)
#pragma unroll
          for (int mi = 0; mi < 4; ++mi)
#pragma unroll
            for (int r = 0; r < 4; ++r) {
              const int row = m0 + qm * 128 + wm * 64 + mi * 16 + rB + r;
              C[(long long)b2 * 2097152 + (long long)row * 2048 + s] =
                  f2bf(acc[qm][qn][mi][ni][r] + X[row]);
            }
      }
  }
}

// =====================================================================
// gemm8_k: 256x128x32 bf16 MFMA GEMM, triple-buffered (R8 core).
// EPI 1: bf16 out * scale (QK^T); EPI 2: f32 out + X[idx] (PV+residual).
// =====================================================================

template<int EPI>
__global__ __launch_bounds__(512, 4) void gemm8_k(
    const short* __restrict__ A, const short* __restrict__ Bt,
    void* __restrict__ Cv, const float* __restrict__ X,
    int K, int lda, int ldb, int ldc,
    long long strA, long long strB, long long strC, long long strX, float scale) {
  __shared__ __align__(16) short Ls[36864];   // 72 KiB

  const int lane = threadIdx.x & 63;
  const int w = threadIdx.x >> 6;
  const int wm = w >> 1, wn = w & 1;
  const int l15 = lane & 15;
  const int g4 = lane >> 4;
  const int swR = ((g4 ^ ((l15 >> 1) & 3)) << 3);
  const int arow = (wm * 64 + l15) * 32 + swR;
  const int brow = (wn * 64 + l15) * 32 + swR;
  const int sg = (lane & 3) ^ ((lane >> 3) & 3);

  const int gx = gridDim.x, gy = gridDim.y;
  const int nwg = gx * gy * gridDim.z;
  int lid = blockIdx.x + gx * (blockIdx.y + gy * blockIdx.z);
  lid = (lid & 7) * (nwg >> 3) + (lid >> 3);
  const int bx = lid % gx;
  const int rem = lid / gx;
  const int by = rem % gy;
  const int bz = rem / gy;

  const int n0 = bx * 128;
  const int m0 = by * 256;
  const int nt = K >> 5;

  const long long ldaB = 2LL * lda, ldbB = 2LL * ldb;
  const long long ldaB16 = 16 * ldaB;

  const char* pA = (const char*)(A + (long long)bz * strA)
      + (long long)(m0 + w * 32 + (lane >> 2)) * ldaB + sg * 16;
  const char* pB = (const char*)(Bt + (long long)bz * strB)
      + (long long)(n0 + w * 16 + (lane >> 2)) * ldbB + sg * 16;

  short* dA = Ls + w * 1024;            // + buf*12288
  short* dB = Ls + 8192 + w * 512;      // + buf*12288

  f32x4 acc[4][4] = {};

  // prologue: stage tiles 0,1,2 -> buffers 0,1,2
#pragma unroll
  for (int i = 0; i < 3; ++i) {
    const char* qA = pA + i * 64;
    gload16(qA,           dA + i * 12288);
    gload16(qA + ldaB16,  dA + i * 12288 + 512);
    gload16(pB + i * 64,  dB + i * 12288);
  }
  asm volatile("s_waitcnt vmcnt(6)" ::: "memory");
  __builtin_amdgcn_s_barrier();

  int cur = 0;
  for (int t = 0; t < nt; ++t) {
    const int bufO = cur * 12288;
    bf16x8 aR[4], bR[4];
#pragma unroll
    for (int mi = 0; mi < 4; ++mi)
      aR[mi] = *(const bf16x8*)(Ls + bufO + arow + mi * 512);
#pragma unroll
    for (int ni = 0; ni < 4; ++ni)
      bR[ni] = *(const bf16x8*)(Ls + bufO + 8192 + brow + ni * 512);
    asm volatile("s_waitcnt lgkmcnt(0)" ::: "memory");
    __builtin_amdgcn_s_barrier();
    if (t + 3 < nt) {
      const char* qA = pA + (t + 3) * 64;
      gload16(qA,          dA + bufO);
      gload16(qA + ldaB16, dA + bufO + 512);
      gload16(pB + (t + 3) * 64, dB + bufO);
    }
    __builtin_amdgcn_sched_barrier(0);
    __builtin_amdgcn_s_setprio(1);
#pragma unroll
    for (int mi = 0; mi < 4; ++mi)
#pragma unroll
      for (int ni = 0; ni < 4; ++ni)
        acc[mi][ni] = __builtin_amdgcn_mfma_f32_16x16x32_bf16(
            aR[mi], bR[ni], acc[mi][ni], 0, 0, 0);
    __builtin_amdgcn_s_setprio(0);
    if (t + 3 < nt)      asm volatile("s_waitcnt vmcnt(6)" ::: "memory");
    else if (t + 2 < nt) asm volatile("s_waitcnt vmcnt(3)" ::: "memory");
    else                 asm volatile("s_waitcnt vmcnt(0)" ::: "memory");
    __builtin_amdgcn_s_barrier();
    cur = (cur == 2) ? 0 : cur + 1;
  }

  // ---- epilogue ----
  const int rB = g4 * 4;
  if (EPI == 1) {
    short* C = (short*)Cv + (long long)bz * strC;
#pragma unroll
    for (int ni = 0; ni < 4; ++ni) {
      const int col = n0 + wn * 64 + ni * 16 + l15;
#pragma unroll
      for (int mi = 0; mi < 4; ++mi)
#pragma unroll
        for (int r = 0; r < 4; ++r) {
          const int row = m0 + wm * 64 + mi * 16 + rB + r;
          C[(long long)row * ldc + col] = f2bf(acc[mi][ni][r] * scale);
        }
    }
  } else {  // EPI == 2
    float* C = (float*)Cv + (long long)bz * strC;
    const float* Xb = X + (long long)bz * strX;
#pragma unroll
    for (int ni = 0; ni < 4; ++ni) {
      const int col = n0 + wn * 64 + ni * 16 + l15;
#pragma unroll
      for (int mi = 0; mi < 4; ++mi)
#pragma unroll
        for (int r = 0; r < 4; ++r) {
          const int row = m0 + wm * 64 + mi * 16 + rB + r;
          const long long idx = (long long)row * ldc + col;
          C[idx] = acc[mi][ni][r] + Xb[idx];
        }
    }
  }
}

// ---------------- row softmax over 2048 (in-place, bf16) ----------------
__global__ __launch_bounds__(256) void softmax_k(short* __restrict__ P) {
  __shared__ float redm[4];
  __shared__ float reds[4];
  const long long row = blockIdx.x;
  short* p = P + row * 2048;
  const int t = threadIdx.x;
  const int w = t >> 6, lane = t & 63;
  bf16x8 v = *(const bf16x8*)(p + t * 8);
  float f[8];
  float mx = -3.0e38f;
#pragma unroll
  for (int j = 0; j < 8; ++j) { f[j] = bf2f(v[j]); mx = fmaxf(mx, f[j]); }
#pragma unroll
  for (int o = 32; o > 0; o >>= 1) mx = fmaxf(mx, __shfl_xor(mx, o));
  if (lane == 0) redm[w] = mx;
  __syncthreads();
  mx = fmaxf(fmaxf(redm[0], redm[1]), fmaxf(redm[2], redm[3]));
  float s = 0.f;
#pragma unroll
  for (int j = 0; j < 8; ++j) { f[j] = __expf(f[j] - mx); s += f[j]; }
#pragma unroll
  for (int o = 32; o > 0; o >>= 1) s += __shfl_xor(s, o);
  if (lane == 0) reds[w] = s;
  __syncthreads();
  s = reds[0] + reds[1] + reds[2] + reds[3];
  const float inv = 1.0f / (s + 1e-6f);
  bf16x8 o8;
#pragma unroll
  for (int j = 0; j < 8; ++j) o8[j] = f2bf(f[j] * inv);
  *(bf16x8*)(p + t * 8) = o8;
}

extern "C" void kernel_launch(void* const* d_in, const int* in_sizes, int n_in,
                              void* d_out, int out_size, void* d_ws, size_t ws_size,
                              hipStream_t stream) {
  const float* x  = (const float*)d_in[0];
  const float* y  = (const float*)d_in[1];
  const float* Wq = (const float*)d_in[2];
  const float* bq = (const float*)d_in[3];
  const float* Wk = (const float*)d_in[4];
  const float* bk = (const float*)d_in[5];
  const float* Wv = (const float*)d_in[6];
  const float* bv = (const float*)d_in[7];
  float* out = (float*)d_out;

  const long long SD  = 2048LL * 1024;
  const long long BSD = 16LL * SD;
  const long long SS  = 2048LL * 2048;

  char* ws = (char*)d_ws;
  short* xb  = (short*)ws;                   // 67.1 MB
  short* yb  = xb + BSD;                     // 67.1 MB
  short* Sl  = (short*)ws;                   // 134.2 MB (aliases xb+yb; written after they die)
  short* Qb  = (short*)(ws + 134217728);     // 67.1 MB
  short* Kb  = Qb + BSD;                     // 67.1 MB
  short* Vt  = Kb + BSD;                     // 67.1 MB  [b][d][s]
  short* Wqt = Vt + BSD;                     // 2 MB each
  short* Wkt = Wqt + 1024 * 1024;
  short* Wvt = Wkt + 1024 * 1024;

  // 1) convert x, y to bf16
  cvt_k<<<2048, 256, 0, stream>>>(x, xb, (int)(BSD / 4));
  cvt_k<<<2048, 256, 0, stream>>>(y, yb, (int)(BSD / 4));

  // 2) transpose+convert weights
  cvtT_k<<<dim3(32, 32), 256, 0, stream>>>(Wq, Wqt);
  cvtT_k<<<dim3(32, 32), 256, 0, stream>>>(Wk, Wkt);
  cvtT_k<<<dim3(32, 32), 256, 0, stream>>>(Wv, Wvt);

  // 3) Q = xb @ Wq + bq  (256^2 8-phase kernel — best for projections)
  gemm256_k<0><<<dim3(4, 128, 1), 512, 0, stream>>>(
      xb, Wqt, Qb, bq, 1024, 1024, 1024, 1024);
  // 4) K = yb @ Wk + bk
  gemm256_k<0><<<dim3(4, 128, 1), 512, 0, stream>>>(
      yb, Wkt, Kb, bk, 1024, 1024, 1024, 1024);
  // 5) V^T: A = Wv^T, Bt = yb -> Vt[b][f][s]
  gemm256_k<3><<<dim3(128, 4, 1), 512, 0, stream>>>(
      Wvt, yb, Vt, bv, 1024, 1024, 1024, 0);

  // 6) logits = Q @ K^T / 32  (256x128 triple-buffer — best for attn GEMMs)
  gemm8_k<1><<<dim3(16, 8, 16), 512, 0, stream>>>(
      Qb, Kb, Sl, nullptr, 1024, 1024, 1024, 2048, SD, SD, SS, 0, 0.03125f);

  // 7) softmax rows (32768 rows of 2048), in-place
  softmax_k<<<32768, 256, 0, stream>>>(Sl);

  // 8) out = P @ V + x
  gemm8_k<2><<<dim3(8, 8, 16), 512, 0, stream>>>(
      Sl, Vt, out, x, 2048, 2048, 2048, 1024, SS, SD, SD, SD, 1.f);

  (void)in_sizes; (void)n_in; (void)out_size; (void)ws_size;
}

// Round 16
// 676.751 us; speedup vs baseline: 2.1971x; 1.0925x over previous
//
#include <hip/hip_runtime.h>
#include <hip/hip_bf16.h>

typedef __attribute__((ext_vector_type(8))) short bf16x8;
typedef __attribute__((ext_vector_type(4))) float f32x4;
typedef __attribute__((ext_vector_type(2))) long i64x2;

__device__ __forceinline__ float bf2f(short u) {
  union { unsigned int u; float f; } c;
  c.u = ((unsigned int)(unsigned short)u) << 16;
  return c.f;
}
__device__ __forceinline__ short f2bf(float f) {
  union { float f; unsigned int u; } c; c.f = f;
  unsigned int r = (c.u + 0x7fffu + ((c.u >> 16) & 1u)) >> 16;
  return (short)(unsigned short)r;
}

__device__ __forceinline__ void gload16(const void* g, void* l) {
  __builtin_amdgcn_global_load_lds(
      (const __attribute__((address_space(1))) unsigned int*)g,
      (__attribute__((address_space(3))) unsigned int*)l, 16, 0, 0);
}

// fp8 interleave within a 64-k group: logical k -> stored byte
//   g4 = (k>>3)&3, kk = (k>>5)&1, b = k&7 :  stored = g4*16 + kk*8 + b
__device__ __forceinline__ int fp8_g(int s) {
  return (s >> 6) * 64 + ((s >> 3) & 3) * 16 + ((s >> 5) & 1) * 8 + (s & 7);
}

// ---------------- fp32 -> bf16 convert ----------------
__global__ __launch_bounds__(256) void cvt_k(const float* __restrict__ in,
                                             short* __restrict__ out, int n4) {
  int i = blockIdx.x * blockDim.x + threadIdx.x;
  const int stride = gridDim.x * blockDim.x;
  for (; i < n4; i += stride) {
    float4 v = ((const float4*)in)[i];
    short4 o;
    o.x = f2bf(v.x); o.y = f2bf(v.y); o.z = f2bf(v.z); o.w = f2bf(v.w);
    ((short4*)out)[i] = o;
  }
}

// ---------------- W [1024][1024] f32 -> W^T bf16 ----------------
__global__ __launch_bounds__(256) void cvtT_k(const float* __restrict__ W,
                                              short* __restrict__ Wt) {
  __shared__ float tile[32][33];
  const int n0 = blockIdx.x * 32, k0 = blockIdx.y * 32;
  const int tr = threadIdx.x >> 5;
  const int tc = threadIdx.x & 31;
#pragma unroll
  for (int p = 0; p < 4; ++p)
    tile[p * 8 + tr][tc] = W[(long long)(k0 + p * 8 + tr) * 1024 + n0 + tc];
  __syncthreads();
#pragma unroll
  for (int p = 0; p < 4; ++p)
    Wt[(long long)(n0 + p * 8 + tr) * 1024 + k0 + tc] = f2bf(tile[tc][p * 8 + tr]);
}

// =====================================================================
// gemm256_k: 256x256x64 8-phase bf16 MFMA GEMM (R6 core, validated)
// EPI 0: bf16 +bias[col] (projections); EPI 3: V^T in fp8-e4m3,
// k-interleaved layout [b][f][G(s)], +bias[row].
// =====================================================================

#define STG6(sp, ld8, dOff) do { \
  gload16((sp), Ls + (dOff)); \
  gload16((const char*)(sp) + (ld8), Ls + (dOff) + 512); } while (0)

#define RD_A6(BUF, QM) do { \
  _Pragma("unroll") \
  for (int mi = 0; mi < 4; ++mi) { \
    aR[mi][0] = *(const bf16x8*)(Ls + (BUF) + (QM)*8192 + arow + mi*1024 + aO0); \
    aR[mi][1] = *(const bf16x8*)(Ls + (BUF) + (QM)*8192 + arow + mi*1024 + aO1); \
  } } while (0)

#define RD_B6(DST, BUF, QN) do { \
  _Pragma("unroll") \
  for (int ni = 0; ni < 2; ++ni) { \
    DST[ni][0] = *(const bf16x8*)(Ls + (BUF) + 16384 + (QN)*8192 + brow + ni*1024 + aO0); \
    DST[ni][1] = *(const bf16x8*)(Ls + (BUF) + 16384 + (QN)*8192 + brow + ni*1024 + aO1); \
  } } while (0)

#define SYNCIN6 do { \
  __builtin_amdgcn_sched_barrier(0); \
  __builtin_amdgcn_s_barrier(); \
  asm volatile("s_waitcnt lgkmcnt(0)" ::: "memory"); \
  __builtin_amdgcn_sched_barrier(0); \
  __builtin_amdgcn_s_setprio(1); } while (0)

#define SYNCOUT6 do { \
  __builtin_amdgcn_s_setprio(0); \
  __builtin_amdgcn_s_barrier(); } while (0)

#define MF166(ACCQ, BB) do { \
  _Pragma("unroll") \
  for (int mi = 0; mi < 4; ++mi) { \
    _Pragma("unroll") \
    for (int ni = 0; ni < 2; ++ni) { \
      ACCQ[mi][ni] = __builtin_amdgcn_mfma_f32_16x16x32_bf16(aR[mi][0], BB[ni][0], ACCQ[mi][ni], 0, 0, 0); \
      ACCQ[mi][ni] = __builtin_amdgcn_mfma_f32_16x16x32_bf16(aR[mi][1], BB[ni][1], ACCQ[mi][ni], 0, 0, 0); \
    } \
  } } while (0)

template<int EPI>
__global__ __launch_bounds__(512) void gemm256_k(
    const short* __restrict__ A, const short* __restrict__ Bt,
    void* __restrict__ Cv, const float* __restrict__ X,
    int K, int lda, int ldb, int ldc) {
  __shared__ __align__(16) short Ls[65536];   // 128 KiB

  const int lane = threadIdx.x & 63;
  const int w = threadIdx.x >> 6;
  const int wm = w >> 2, wn = w & 3;
  const int w1k = w * 1024;
  const int l15 = lane & 15;
  const int g4 = lane >> 4;
  const int p8 = lane & 7;
  const int r8 = lane >> 3;
  const int aO0 = (g4 ^ p8) << 3;
  const int aO1 = ((4 + g4) ^ p8) << 3;
  const int arow = (wm * 64 + l15) * 64;
  const int brow = (wn * 32 + l15) * 64;

  const int gx = gridDim.x, gy = gridDim.y;
  const int nwg = gx * gy * gridDim.z;
  int lid = blockIdx.x + gx * (blockIdx.y + gy * blockIdx.z);
  lid = (lid & 7) * (nwg >> 3) + (lid >> 3);
  const int bx = lid % gx;
  const int rem = lid / gx;
  const int by = rem % gy;

  const int n0 = bx * 256;
  const int m0 = by * 256;
  const int nt = K >> 6;
  const int nit = nt >> 1;

  const long long ldaB = 2LL * lda, ldbB = 2LL * ldb;
  const long long ldaB8 = 8 * ldaB, ldbB8 = 8 * ldbB;
  const long long hOffA = 128 * ldaB, hOffB = 128 * ldbB;

  const char* pA = (const char*)A
      + (long long)(m0 + w * 16 + r8) * ldaB + ((p8 ^ r8) << 4);
  const char* pB = (const char*)Bt
      + (long long)(n0 + w * 16 + r8) * ldbB + ((p8 ^ r8) << 4);

  f32x4 acc[2][2][4][2] = {};
  bf16x8 aR[4][2], bR0[2][2], bR1[2][2];

  STG6(pA,                 ldaB8, 0 + w1k);
  STG6(pA + hOffA,         ldaB8, 8192 + w1k);
  STG6(pB,                 ldbB8, 16384 + w1k);
  STG6(pB + hOffB,         ldbB8, 24576 + w1k);
  STG6(pA + 128,           ldaB8, 32768 + w1k);
  STG6(pA + 128 + hOffA,   ldaB8, 40960 + w1k);
  STG6(pB + 128,           ldbB8, 49152 + w1k);
  STG6(pB + 128 + hOffB,   ldbB8, 57344 + w1k);
  asm volatile("s_waitcnt vmcnt(8)" ::: "memory");
  __builtin_amdgcn_s_barrier();

  for (int j = 0; j < nit; ++j) {
    const bool st = (j + 1 < nit);

    RD_A6(0, 0); RD_B6(bR0, 0, 0);
    SYNCIN6; MF166(acc[0][0], bR0); SYNCOUT6;
    RD_B6(bR1, 0, 1);
    if (st) { STG6(pA + 256, ldaB8, 0 + w1k);
              STG6(pB + 256, ldbB8, 16384 + w1k); }
    SYNCIN6; MF166(acc[0][1], bR1); SYNCOUT6;
    RD_A6(0, 1);
    if (st) STG6(pB + 256 + hOffB, ldbB8, 24576 + w1k);
    SYNCIN6; MF166(acc[1][1], bR1); SYNCOUT6;
    if (st) STG6(pA + 256 + hOffA, ldaB8, 8192 + w1k);
    SYNCIN6; MF166(acc[1][0], bR0);
    __builtin_amdgcn_s_setprio(0);
    if (st) asm volatile("s_waitcnt vmcnt(8)" ::: "memory");
    else    asm volatile("s_waitcnt vmcnt(0)" ::: "memory");
    __builtin_amdgcn_s_barrier();

    RD_A6(32768, 0); RD_B6(bR0, 32768, 0);
    SYNCIN6; MF166(acc[0][0], bR0); SYNCOUT6;
    RD_B6(bR1, 32768, 1);
    if (st) { STG6(pA + 384, ldaB8, 32768 + w1k);
              STG6(pB + 384, ldbB8, 49152 + w1k); }
    SYNCIN6; MF166(acc[0][1], bR1); SYNCOUT6;
    RD_A6(32768, 1);
    if (st) STG6(pB + 384 + hOffB, ldbB8, 57344 + w1k);
    SYNCIN6; MF166(acc[1][1], bR1); SYNCOUT6;
    if (st) STG6(pA + 384 + hOffA, ldaB8, 40960 + w1k);
    SYNCIN6; MF166(acc[1][0], bR0);
    __builtin_amdgcn_s_setprio(0);
    if (st) asm volatile("s_waitcnt vmcnt(8)" ::: "memory");
    __builtin_amdgcn_s_barrier();

    pA += 256; pB += 256;
  }

  const int rB = g4 * 4;
  if (EPI == 0) {
    short* C = (short*)Cv;
#pragma unroll
    for (int qn = 0; qn < 2; ++qn)
#pragma unroll
      for (int ni = 0; ni < 2; ++ni) {
        const int col = n0 + qn * 128 + wn * 32 + ni * 16 + l15;
        const float bv = X[col];
#pragma unroll
        for (int qm = 0; qm < 2; ++qm)
#pragma unroll
          for (int mi = 0; mi < 4; ++mi)
#pragma unroll
            for (int r = 0; r < 4; ++r) {
              const int row = m0 + qm * 128 + wm * 64 + mi * 16 + rB + r;
              C[(long long)row * ldc + col] = f2bf(acc[qm][qn][mi][ni][r] + bv);
            }
      }
  } else {  // EPI == 3: V^T fp8-e4m3, [b][f=row][G(s)], n = b*2048 + s
    unsigned char* C = (unsigned char*)Cv;
#pragma unroll
    for (int qn = 0; qn < 2; ++qn)
#pragma unroll
      for (int ni = 0; ni < 2; ++ni) {
        const int col = n0 + qn * 128 + wn * 32 + ni * 16 + l15;
        const int b2 = col >> 11;
        const int s = col & 2047;
        const int gs = fp8_g(s);
#pragma unroll
        for (int qm = 0; qm < 2; ++qm)
#pragma unroll
          for (int mi = 0; mi < 4; ++mi)
#pragma unroll
            for (int r = 0; r < 4; ++r) {
              const int row = m0 + qm * 128 + wm * 64 + mi * 16 + rB + r;
              const float v = acc[qm][qn][mi][ni][r] + X[row];
              const unsigned d = __builtin_amdgcn_cvt_pk_fp8_f32(v, v, 0, false);
              C[(long long)b2 * 2097152 + (long long)row * 2048 + gs] =
                  (unsigned char)(d & 0xff);
            }
      }
  }
}

// =====================================================================
// gemm8_k: 256x128x32 bf16 MFMA GEMM, triple-buffered (R8 core).
// EPI 1: bf16 out * scale (QK^T).
// =====================================================================

template<int EPI>
__global__ __launch_bounds__(512, 4) void gemm8_k(
    const short* __restrict__ A, const short* __restrict__ Bt,
    void* __restrict__ Cv, const float* __restrict__ X,
    int K, int lda, int ldb, int ldc,
    long long strA, long long strB, long long strC, long long strX, float scale) {
  __shared__ __align__(16) short Ls[36864];   // 72 KiB

  const int lane = threadIdx.x & 63;
  const int w = threadIdx.x >> 6;
  const int wm = w >> 1, wn = w & 1;
  const int l15 = lane & 15;
  const int g4 = lane >> 4;
  const int swR = ((g4 ^ ((l15 >> 1) & 3)) << 3);
  const int arow = (wm * 64 + l15) * 32 + swR;
  const int brow = (wn * 64 + l15) * 32 + swR;
  const int sg = (lane & 3) ^ ((lane >> 3) & 3);

  const int gx = gridDim.x, gy = gridDim.y;
  const int nwg = gx * gy * gridDim.z;
  int lid = blockIdx.x + gx * (blockIdx.y + gy * blockIdx.z);
  lid = (lid & 7) * (nwg >> 3) + (lid >> 3);
  const int bx = lid % gx;
  const int rem = lid / gx;
  const int by = rem % gy;
  const int bz = rem / gy;

  const int n0 = bx * 128;
  const int m0 = by * 256;
  const int nt = K >> 5;

  const long long ldaB = 2LL * lda, ldbB = 2LL * ldb;
  const long long ldaB16 = 16 * ldaB;

  const char* pA = (const char*)(A + (long long)bz * strA)
      + (long long)(m0 + w * 32 + (lane >> 2)) * ldaB + sg * 16;
  const char* pB = (const char*)(Bt + (long long)bz * strB)
      + (long long)(n0 + w * 16 + (lane >> 2)) * ldbB + sg * 16;

  short* dA = Ls + w * 1024;            // + buf*12288
  short* dB = Ls + 8192 + w * 512;      // + buf*12288

  f32x4 acc[4][4] = {};

#pragma unroll
  for (int i = 0; i < 3; ++i) {
    const char* qA = pA + i * 64;
    gload16(qA,           dA + i * 12288);
    gload16(qA + ldaB16,  dA + i * 12288 + 512);
    gload16(pB + i * 64,  dB + i * 12288);
  }
  asm volatile("s_waitcnt vmcnt(6)" ::: "memory");
  __builtin_amdgcn_s_barrier();

  int cur = 0;
  for (int t = 0; t < nt; ++t) {
    const int bufO = cur * 12288;
    bf16x8 aR[4], bR[4];
#pragma unroll
    for (int mi = 0; mi < 4; ++mi)
      aR[mi] = *(const bf16x8*)(Ls + bufO + arow + mi * 512);
#pragma unroll
    for (int ni = 0; ni < 4; ++ni)
      bR[ni] = *(const bf16x8*)(Ls + bufO + 8192 + brow + ni * 512);
    asm volatile("s_waitcnt lgkmcnt(0)" ::: "memory");
    __builtin_amdgcn_s_barrier();
    if (t + 3 < nt) {
      const char* qA = pA + (t + 3) * 64;
      gload16(qA,          dA + bufO);
      gload16(qA + ldaB16, dA + bufO + 512);
      gload16(pB + (t + 3) * 64, dB + bufO);
    }
    __builtin_amdgcn_sched_barrier(0);
    __builtin_amdgcn_s_setprio(1);
#pragma unroll
    for (int mi = 0; mi < 4; ++mi)
#pragma unroll
      for (int ni = 0; ni < 4; ++ni)
        acc[mi][ni] = __builtin_amdgcn_mfma_f32_16x16x32_bf16(
            aR[mi], bR[ni], acc[mi][ni], 0, 0, 0);
    __builtin_amdgcn_s_setprio(0);
    if (t + 3 < nt)      asm volatile("s_waitcnt vmcnt(6)" ::: "memory");
    else if (t + 2 < nt) asm volatile("s_waitcnt vmcnt(3)" ::: "memory");
    else                 asm volatile("s_waitcnt vmcnt(0)" ::: "memory");
    __builtin_amdgcn_s_barrier();
    cur = (cur == 2) ? 0 : cur + 1;
  }

  const int rB = g4 * 4;
  short* C = (short*)Cv + (long long)bz * strC;
#pragma unroll
  for (int ni = 0; ni < 4; ++ni) {
    const int col = n0 + wn * 64 + ni * 16 + l15;
#pragma unroll
    for (int mi = 0; mi < 4; ++mi)
#pragma unroll
      for (int r = 0; r < 4; ++r) {
        const int row = m0 + wm * 64 + mi * 16 + rB + r;
        C[(long long)row * ldc + col] = f2bf(acc[mi][ni][r] * scale);
      }
  }
  (void)X; (void)strX;
}

// ---------- row softmax over 2048: bf16 in -> fp8 (x256, interleaved) ----------
__global__ __launch_bounds__(256) void softmax8_k(const short* __restrict__ Sl,
                                                  unsigned char* __restrict__ P8) {
  __shared__ float redm[4];
  __shared__ float reds[4];
  const long long row = blockIdx.x;
  const short* p = Sl + row * 2048;
  const int t = threadIdx.x;
  const int w = t >> 6, lane = t & 63;
  bf16x8 v = *(const bf16x8*)(p + t * 8);
  float f[8];
  float mx = -3.0e38f;
#pragma unroll
  for (int j = 0; j < 8; ++j) { f[j] = bf2f(v[j]); mx = fmaxf(mx, f[j]); }
#pragma unroll
  for (int o = 32; o > 0; o >>= 1) mx = fmaxf(mx, __shfl_xor(mx, o));
  if (lane == 0) redm[w] = mx;
  __syncthreads();
  mx = fmaxf(fmaxf(redm[0], redm[1]), fmaxf(redm[2], redm[3]));
  float s = 0.f;
#pragma unroll
  for (int j = 0; j < 8; ++j) { f[j] = __expf(f[j] - mx); s += f[j]; }
#pragma unroll
  for (int o = 32; o > 0; o >>= 1) s += __shfl_xor(s, o);
  if (lane == 0) reds[w] = s;
  __syncthreads();
  s = reds[0] + reds[1] + reds[2] + reds[3];
  const float inv = 256.0f / (s + 1e-6f);   // P' = 256 * P (e4m3 range fit)
  unsigned d0 = __builtin_amdgcn_cvt_pk_fp8_f32(f[0] * inv, f[1] * inv, 0, false);
  d0 = __builtin_amdgcn_cvt_pk_fp8_f32(f[2] * inv, f[3] * inv, d0, true);
  unsigned d1 = __builtin_amdgcn_cvt_pk_fp8_f32(f[4] * inv, f[5] * inv, 0, false);
  d1 = __builtin_amdgcn_cvt_pk_fp8_f32(f[6] * inv, f[7] * inv, d1, true);
  const int grp = t >> 3, pc = t & 7;
  unsigned char* dst = P8 + row * 2048 + grp * 64 + (pc & 3) * 16 + (pc >> 2) * 8;
  *(unsigned long long*)dst =
      (unsigned long long)d0 | ((unsigned long long)d1 << 32);
}

// =====================================================================
// pv8_k: out = P @ V + x in fp8 (R8-core addressing, BK=64 fp8).
// A = P8 [b][m][G(s)] (256*P in e4m3), B = V8 [b][f][G(s)].
// Rows 64B, 4x16B slots, same swizzle/vmcnt ledger as gemm8_k.
// ds_read_b128 per fragment = kk0 (dwords 0-1) + kk1 (dwords 2-3).
// Epilogue: f32 out * (1/256) + x residual.
// =====================================================================

__global__ __launch_bounds__(512, 4) void pv8_k(
    const unsigned char* __restrict__ P8, const unsigned char* __restrict__ V8,
    float* __restrict__ Out, const float* __restrict__ x) {
  __shared__ __align__(16) char Ls[73728];   // 3 bufs x (A 16KB + B 8KB)

  const int lane = threadIdx.x & 63;
  const int w = threadIdx.x >> 6;
  const int wm = w >> 1, wn = w & 1;
  const int l15 = lane & 15;
  const int g4 = lane >> 4;
  const int swB = ((g4 ^ ((l15 >> 1) & 3)) << 4);   // byte slot offset
  const int arow = (wm * 64 + l15) * 64 + swB;
  const int brow = (wn * 64 + l15) * 64 + swB;
  const int sg = (lane & 3) ^ ((lane >> 3) & 3);

  const int nwg = 1024;                 // grid (8,8,16)
  int lid = blockIdx.x + 8 * (blockIdx.y + 8 * blockIdx.z);
  lid = (lid & 7) * (nwg >> 3) + (lid >> 3);
  const int bx = lid % 8;
  const int rem = lid / 8;
  const int by = rem % 8;
  const int bz = rem / 8;
  const int n0 = bx * 128, m0 = by * 256;
  const int nt = 32;                    // K = 2048, BK = 64 (fp8)

  const long long SD = 2097152LL;
  const char* pA = (const char*)P8 + (long long)bz * 4194304LL
      + (long long)(m0 + w * 32 + (lane >> 2)) * 2048 + sg * 16;
  const char* pB = (const char*)V8 + (long long)bz * 2097152LL
      + (long long)(n0 + w * 16 + (lane >> 2)) * 2048 + sg * 16;

  char* dA = Ls + w * 2048;             // + buf*24576
  char* dB = Ls + 16384 + w * 1024;     // + buf*24576

  f32x4 acc[4][4] = {};

  // prologue: stage tiles 0,1,2 -> buffers 0,1,2
#pragma unroll
  for (int i = 0; i < 3; ++i) {
    const char* qA = pA + i * 64;
    gload16(qA,              dA + i * 24576);
    gload16(qA + 16 * 2048,  dA + i * 24576 + 1024);
    gload16(pB + i * 64,     dB + i * 24576);
  }
  asm volatile("s_waitcnt vmcnt(6)" ::: "memory");
  __builtin_amdgcn_s_barrier();

  int cur = 0;
  for (int t = 0; t < nt; ++t) {
    const int bufO = cur * 24576;
    i64x2 aA[4], bB[4];
#pragma unroll
    for (int mi = 0; mi < 4; ++mi)
      aA[mi] = *(const i64x2*)(Ls + bufO + arow + mi * 1024);
#pragma unroll
    for (int ni = 0; ni < 4; ++ni)
      bB[ni] = *(const i64x2*)(Ls + bufO + 16384 + brow + ni * 1024);
    asm volatile("s_waitcnt lgkmcnt(0)" ::: "memory");
    __builtin_amdgcn_s_barrier();
    if (t + 3 < nt) {
      const char* qA = pA + (t + 3) * 64;
      gload16(qA,             dA + bufO);
      gload16(qA + 16 * 2048, dA + bufO + 1024);
      gload16(pB + (t + 3) * 64, dB + bufO);
    }
    __builtin_amdgcn_sched_barrier(0);
    __builtin_amdgcn_s_setprio(1);
#pragma unroll
    for (int mi = 0; mi < 4; ++mi)
#pragma unroll
      for (int ni = 0; ni < 4; ++ni) {
        acc[mi][ni] = __builtin_amdgcn_mfma_f32_16x16x32_fp8_fp8(
            aA[mi][0], bB[ni][0], acc[mi][ni], 0, 0, 0);
        acc[mi][ni] = __builtin_amdgcn_mfma_f32_16x16x32_fp8_fp8(
            aA[mi][1], bB[ni][1], acc[mi][ni], 0, 0, 0);
      }
    __builtin_amdgcn_s_setprio(0);
    if (t + 3 < nt)      asm volatile("s_waitcnt vmcnt(6)" ::: "memory");
    else if (t + 2 < nt) asm volatile("s_waitcnt vmcnt(3)" ::: "memory");
    else                 asm volatile("s_waitcnt vmcnt(0)" ::: "memory");
    __builtin_amdgcn_s_barrier();
    cur = (cur == 2) ? 0 : cur + 1;
  }

  // epilogue: f32 out * (1/256) + residual
  const int rB = g4 * 4;
  float* C = Out + (long long)bz * SD;
  const float* Xb = x + (long long)bz * SD;
#pragma unroll
  for (int ni = 0; ni < 4; ++ni) {
    const int col = n0 + wn * 64 + ni * 16 + l15;
#pragma unroll
    for (int mi = 0; mi < 4; ++mi)
#pragma unroll
      for (int r = 0; r < 4; ++r) {
        const int row = m0 + wm * 64 + mi * 16 + rB + r;
        const long long idx = (long long)row * 1024 + col;
        C[idx] = acc[mi][ni][r] * 0.00390625f + Xb[idx];
      }
  }
}

extern "C" void kernel_launch(void* const* d_in, const int* in_sizes, int n_in,
                              void* d_out, int out_size, void* d_ws, size_t ws_size,
                              hipStream_t stream) {
  const float* x  = (const float*)d_in[0];
  const float* y  = (const float*)d_in[1];
  const float* Wq = (const float*)d_in[2];
  const float* bq = (const float*)d_in[3];
  const float* Wk = (const float*)d_in[4];
  const float* bk = (const float*)d_in[5];
  const float* Wv = (const float*)d_in[6];
  const float* bv = (const float*)d_in[7];
  float* out = (float*)d_out;

  const long long SD  = 2048LL * 1024;
  const long long BSD = 16LL * SD;
  const long long SS  = 2048LL * 2048;

  char* ws = (char*)d_ws;
  short* xb  = (short*)ws;                   // 67.1 MB
  short* yb  = xb + BSD;                     // 67.1 MB
  short* Sl  = (short*)ws;                   // 134.2 MB (aliases xb+yb)
  short* Qb  = (short*)(ws + 134217728);     // 67.1 MB (dead after QK^T)
  unsigned char* P8 = (unsigned char*)Qb;    // 67.1 MB fp8 P (reuses Qb)
  short* Kb  = Qb + BSD;                     // 67.1 MB
  short* Vt  = Kb + BSD;                     // region holds V8 (33.5 MB fp8)
  unsigned char* V8 = (unsigned char*)Vt;
  short* Wqt = Vt + BSD;                     // 2 MB each
  short* Wkt = Wqt + 1024 * 1024;
  short* Wvt = Wkt + 1024 * 1024;

  // 1) convert x, y to bf16
  cvt_k<<<2048, 256, 0, stream>>>(x, xb, (int)(BSD / 4));
  cvt_k<<<2048, 256, 0, stream>>>(y, yb, (int)(BSD / 4));

  // 2) transpose+convert weights
  cvtT_k<<<dim3(32, 32), 256, 0, stream>>>(Wq, Wqt);
  cvtT_k<<<dim3(32, 32), 256, 0, stream>>>(Wk, Wkt);
  cvtT_k<<<dim3(32, 32), 256, 0, stream>>>(Wv, Wvt);

  // 3) Q = xb @ Wq + bq
  gemm256_k<0><<<dim3(4, 128, 1), 512, 0, stream>>>(
      xb, Wqt, Qb, bq, 1024, 1024, 1024, 1024);
  // 4) K = yb @ Wk + bk
  gemm256_k<0><<<dim3(4, 128, 1), 512, 0, stream>>>(
      yb, Wkt, Kb, bk, 1024, 1024, 1024, 1024);
  // 5) V^T fp8: A = Wv^T, Bt = yb -> V8[b][f][G(s)]
  gemm256_k<3><<<dim3(128, 4, 1), 512, 0, stream>>>(
      Wvt, yb, V8, bv, 1024, 1024, 1024, 0);

  // 6) logits = Q @ K^T / 32  -> Sl bf16
  gemm8_k<1><<<dim3(16, 8, 16), 512, 0, stream>>>(
      Qb, Kb, Sl, nullptr, 1024, 1024, 1024, 2048, SD, SD, SS, 0, 0.03125f);

  // 7) softmax rows -> P8 = e4m3(256 * P), k-interleaved (overwrites Qb)
  softmax8_k<<<32768, 256, 0, stream>>>(Sl, P8);

  // 8) out = (P8 @ V8) / 256 + x
  pv8_k<<<dim3(8, 8, 16), 512, 0, stream>>>(P8, V8, out, x);

  (void)in_sizes; (void)n_in; (void)out_size; (void)ws_size;
}

// Round 17
// 616.339 us; speedup vs baseline: 2.4125x; 1.0980x over previous
//
#include <hip/hip_runtime.h>
#include <hip/hip_bf16.h>

typedef __attribute__((ext_vector_type(8))) short bf16x8;
typedef __attribute__((ext_vector_type(4))) float f32x4;
typedef __attribute__((ext_vector_type(2))) long i64x2;

__device__ __forceinline__ float bf2f(short u) {
  union { unsigned int u; float f; } c;
  c.u = ((unsigned int)(unsigned short)u) << 16;
  return c.f;
}
__device__ __forceinline__ short f2bf(float f) {
  union { float f; unsigned int u; } c; c.f = f;
  unsigned int r = (c.u + 0x7fffu + ((c.u >> 16) & 1u)) >> 16;
  return (short)(unsigned short)r;
}

__device__ __forceinline__ void gload16(const void* g, void* l) {
  __builtin_amdgcn_global_load_lds(
      (const __attribute__((address_space(1))) unsigned int*)g,
      (__attribute__((address_space(3))) unsigned int*)l, 16, 0, 0);
}

// fp8 interleave within a 64-k group: logical k -> stored byte
//   kk = (k>>5)&1, g4 = (k>>3)&3, b = k&7 :  stored = g4*16 + kk*8 + b
__device__ __forceinline__ int fp8_g(int s) {
  return (s >> 6) * 64 + ((s >> 3) & 3) * 16 + ((s >> 5) & 1) * 8 + (s & 7);
}

// ---------------- fp32 -> bf16 convert ----------------
__global__ __launch_bounds__(256) void cvt_k(const float* __restrict__ in,
                                             short* __restrict__ out, int n4) {
  int i = blockIdx.x * blockDim.x + threadIdx.x;
  const int stride = gridDim.x * blockDim.x;
  for (; i < n4; i += stride) {
    float4 v = ((const float4*)in)[i];
    short4 o;
    o.x = f2bf(v.x); o.y = f2bf(v.y); o.z = f2bf(v.z); o.w = f2bf(v.w);
    ((short4*)out)[i] = o;
  }
}

// ---------------- W [1024][1024] f32 -> W^T bf16 ----------------
__global__ __launch_bounds__(256) void cvtT_k(const float* __restrict__ W,
                                              short* __restrict__ Wt) {
  __shared__ float tile[32][33];
  const int n0 = blockIdx.x * 32, k0 = blockIdx.y * 32;
  const int tr = threadIdx.x >> 5;
  const int tc = threadIdx.x & 31;
#pragma unroll
  for (int p = 0; p < 4; ++p)
    tile[p * 8 + tr][tc] = W[(long long)(k0 + p * 8 + tr) * 1024 + n0 + tc];
  __syncthreads();
#pragma unroll
  for (int p = 0; p < 4; ++p)
    Wt[(long long)(n0 + p * 8 + tr) * 1024 + k0 + tc] = f2bf(tile[tc][p * 8 + tr]);
}

// =====================================================================
// gemm256_k: 256x256x64 8-phase bf16 MFMA GEMM (R6 core, validated)
// EPI 3: V^T fp8-e4m3 [b][f][G(s)], +bias[row].
// EPI 4: fp8-e4m3 row-major [row][G(col)], +bias[col]  (Q/K projections).
// =====================================================================

#define STG6(sp, ld8, dOff) do { \
  gload16((sp), Ls + (dOff)); \
  gload16((const char*)(sp) + (ld8), Ls + (dOff) + 512); } while (0)

#define RD_A6(BUF, QM) do { \
  _Pragma("unroll") \
  for (int mi = 0; mi < 4; ++mi) { \
    aR[mi][0] = *(const bf16x8*)(Ls + (BUF) + (QM)*8192 + arow + mi*1024 + aO0); \
    aR[mi][1] = *(const bf16x8*)(Ls + (BUF) + (QM)*8192 + arow + mi*1024 + aO1); \
  } } while (0)

#define RD_B6(DST, BUF, QN) do { \
  _Pragma("unroll") \
  for (int ni = 0; ni < 2; ++ni) { \
    DST[ni][0] = *(const bf16x8*)(Ls + (BUF) + 16384 + (QN)*8192 + brow + ni*1024 + aO0); \
    DST[ni][1] = *(const bf16x8*)(Ls + (BUF) + 16384 + (QN)*8192 + brow + ni*1024 + aO1); \
  } } while (0)

#define SYNCIN6 do { \
  __builtin_amdgcn_sched_barrier(0); \
  __builtin_amdgcn_s_barrier(); \
  asm volatile("s_waitcnt lgkmcnt(0)" ::: "memory"); \
  __builtin_amdgcn_sched_barrier(0); \
  __builtin_amdgcn_s_setprio(1); } while (0)

#define SYNCOUT6 do { \
  __builtin_amdgcn_s_setprio(0); \
  __builtin_amdgcn_s_barrier(); } while (0)

#define MF166(ACCQ, BB) do { \
  _Pragma("unroll") \
  for (int mi = 0; mi < 4; ++mi) { \
    _Pragma("unroll") \
    for (int ni = 0; ni < 2; ++ni) { \
      ACCQ[mi][ni] = __builtin_amdgcn_mfma_f32_16x16x32_bf16(aR[mi][0], BB[ni][0], ACCQ[mi][ni], 0, 0, 0); \
      ACCQ[mi][ni] = __builtin_amdgcn_mfma_f32_16x16x32_bf16(aR[mi][1], BB[ni][1], ACCQ[mi][ni], 0, 0, 0); \
    } \
  } } while (0)

template<int EPI>
__global__ __launch_bounds__(512) void gemm256_k(
    const short* __restrict__ A, const short* __restrict__ Bt,
    void* __restrict__ Cv, const float* __restrict__ X,
    int K, int lda, int ldb, int ldc) {
  __shared__ __align__(16) short Ls[65536];   // 128 KiB

  const int lane = threadIdx.x & 63;
  const int w = threadIdx.x >> 6;
  const int wm = w >> 2, wn = w & 3;
  const int w1k = w * 1024;
  const int l15 = lane & 15;
  const int g4 = lane >> 4;
  const int p8 = lane & 7;
  const int r8 = lane >> 3;
  const int aO0 = (g4 ^ p8) << 3;
  const int aO1 = ((4 + g4) ^ p8) << 3;
  const int arow = (wm * 64 + l15) * 64;
  const int brow = (wn * 32 + l15) * 64;

  const int gx = gridDim.x, gy = gridDim.y;
  const int nwg = gx * gy * gridDim.z;
  int lid = blockIdx.x + gx * (blockIdx.y + gy * blockIdx.z);
  lid = (lid & 7) * (nwg >> 3) + (lid >> 3);
  const int bx = lid % gx;
  const int rem = lid / gx;
  const int by = rem % gy;

  const int n0 = bx * 256;
  const int m0 = by * 256;
  const int nt = K >> 6;
  const int nit = nt >> 1;

  const long long ldaB = 2LL * lda, ldbB = 2LL * ldb;
  const long long ldaB8 = 8 * ldaB, ldbB8 = 8 * ldbB;
  const long long hOffA = 128 * ldaB, hOffB = 128 * ldbB;

  const char* pA = (const char*)A
      + (long long)(m0 + w * 16 + r8) * ldaB + ((p8 ^ r8) << 4);
  const char* pB = (const char*)Bt
      + (long long)(n0 + w * 16 + r8) * ldbB + ((p8 ^ r8) << 4);

  f32x4 acc[2][2][4][2] = {};
  bf16x8 aR[4][2], bR0[2][2], bR1[2][2];

  STG6(pA,                 ldaB8, 0 + w1k);
  STG6(pA + hOffA,         ldaB8, 8192 + w1k);
  STG6(pB,                 ldbB8, 16384 + w1k);
  STG6(pB + hOffB,         ldbB8, 24576 + w1k);
  STG6(pA + 128,           ldaB8, 32768 + w1k);
  STG6(pA + 128 + hOffA,   ldaB8, 40960 + w1k);
  STG6(pB + 128,           ldbB8, 49152 + w1k);
  STG6(pB + 128 + hOffB,   ldbB8, 57344 + w1k);
  asm volatile("s_waitcnt vmcnt(8)" ::: "memory");
  __builtin_amdgcn_s_barrier();

  for (int j = 0; j < nit; ++j) {
    const bool st = (j + 1 < nit);

    RD_A6(0, 0); RD_B6(bR0, 0, 0);
    SYNCIN6; MF166(acc[0][0], bR0); SYNCOUT6;
    RD_B6(bR1, 0, 1);
    if (st) { STG6(pA + 256, ldaB8, 0 + w1k);
              STG6(pB + 256, ldbB8, 16384 + w1k); }
    SYNCIN6; MF166(acc[0][1], bR1); SYNCOUT6;
    RD_A6(0, 1);
    if (st) STG6(pB + 256 + hOffB, ldbB8, 24576 + w1k);
    SYNCIN6; MF166(acc[1][1], bR1); SYNCOUT6;
    if (st) STG6(pA + 256 + hOffA, ldaB8, 8192 + w1k);
    SYNCIN6; MF166(acc[1][0], bR0);
    __builtin_amdgcn_s_setprio(0);
    if (st) asm volatile("s_waitcnt vmcnt(8)" ::: "memory");
    else    asm volatile("s_waitcnt vmcnt(0)" ::: "memory");
    __builtin_amdgcn_s_barrier();

    RD_A6(32768, 0); RD_B6(bR0, 32768, 0);
    SYNCIN6; MF166(acc[0][0], bR0); SYNCOUT6;
    RD_B6(bR1, 32768, 1);
    if (st) { STG6(pA + 384, ldaB8, 32768 + w1k);
              STG6(pB + 384, ldbB8, 49152 + w1k); }
    SYNCIN6; MF166(acc[0][1], bR1); SYNCOUT6;
    RD_A6(32768, 1);
    if (st) STG6(pB + 384 + hOffB, ldbB8, 57344 + w1k);
    SYNCIN6; MF166(acc[1][1], bR1); SYNCOUT6;
    if (st) STG6(pA + 384 + hOffA, ldaB8, 40960 + w1k);
    SYNCIN6; MF166(acc[1][0], bR0);
    __builtin_amdgcn_s_setprio(0);
    if (st) asm volatile("s_waitcnt vmcnt(8)" ::: "memory");
    __builtin_amdgcn_s_barrier();

    pA += 256; pB += 256;
  }

  const int rB = g4 * 4;
  if (EPI == 3) {  // V^T fp8, [b][f=row][G(s)], n = b*2048 + s
    unsigned char* C = (unsigned char*)Cv;
#pragma unroll
    for (int qn = 0; qn < 2; ++qn)
#pragma unroll
      for (int ni = 0; ni < 2; ++ni) {
        const int col = n0 + qn * 128 + wn * 32 + ni * 16 + l15;
        const int b2 = col >> 11;
        const int s = col & 2047;
        const int gs = fp8_g(s);
#pragma unroll
        for (int qm = 0; qm < 2; ++qm)
#pragma unroll
          for (int mi = 0; mi < 4; ++mi)
#pragma unroll
            for (int r = 0; r < 4; ++r) {
              const int row = m0 + qm * 128 + wm * 64 + mi * 16 + rB + r;
              const float v = acc[qm][qn][mi][ni][r] + X[row];
              const unsigned d = __builtin_amdgcn_cvt_pk_fp8_f32(v, v, 0, false);
              C[(long long)b2 * 2097152 + (long long)row * 2048 + gs] =
                  (unsigned char)(d & 0xff);
            }
      }
  } else {  // EPI == 4: fp8 row-major [row][G(col)], +bias[col]
    unsigned char* C = (unsigned char*)Cv;
#pragma unroll
    for (int qn = 0; qn < 2; ++qn)
#pragma unroll
      for (int ni = 0; ni < 2; ++ni) {
        const int col = n0 + qn * 128 + wn * 32 + ni * 16 + l15;
        const int gs = fp8_g(col);
        const float bv = X[col];
#pragma unroll
        for (int qm = 0; qm < 2; ++qm)
#pragma unroll
          for (int mi = 0; mi < 4; ++mi)
#pragma unroll
            for (int r = 0; r < 4; ++r) {
              const int row = m0 + qm * 128 + wm * 64 + mi * 16 + rB + r;
              const float v = acc[qm][qn][mi][ni][r] + bv;
              const unsigned d = __builtin_amdgcn_cvt_pk_fp8_f32(v, v, 0, false);
              C[(long long)row * ldc + gs] = (unsigned char)(d & 0xff);
            }
      }
  }
}

// ---------- row softmax over 2048: bf16 in -> fp8 (x256, interleaved) ----------
__global__ __launch_bounds__(256) void softmax8_k(const short* __restrict__ Sl,
                                                  unsigned char* __restrict__ P8) {
  __shared__ float redm[4];
  __shared__ float reds[4];
  const long long row = blockIdx.x;
  const short* p = Sl + row * 2048;
  const int t = threadIdx.x;
  const int w = t >> 6, lane = t & 63;
  bf16x8 v = *(const bf16x8*)(p + t * 8);
  float f[8];
  float mx = -3.0e38f;
#pragma unroll
  for (int j = 0; j < 8; ++j) { f[j] = bf2f(v[j]); mx = fmaxf(mx, f[j]); }
#pragma unroll
  for (int o = 32; o > 0; o >>= 1) mx = fmaxf(mx, __shfl_xor(mx, o));
  if (lane == 0) redm[w] = mx;
  __syncthreads();
  mx = fmaxf(fmaxf(redm[0], redm[1]), fmaxf(redm[2], redm[3]));
  float s = 0.f;
#pragma unroll
  for (int j = 0; j < 8; ++j) { f[j] = __expf(f[j] - mx); s += f[j]; }
#pragma unroll
  for (int o = 32; o > 0; o >>= 1) s += __shfl_xor(s, o);
  if (lane == 0) reds[w] = s;
  __syncthreads();
  s = reds[0] + reds[1] + reds[2] + reds[3];
  const float inv = 256.0f / (s + 1e-6f);   // P' = 256 * P (e4m3 range fit)
  unsigned d0 = __builtin_amdgcn_cvt_pk_fp8_f32(f[0] * inv, f[1] * inv, 0, false);
  d0 = __builtin_amdgcn_cvt_pk_fp8_f32(f[2] * inv, f[3] * inv, d0, true);
  unsigned d1 = __builtin_amdgcn_cvt_pk_fp8_f32(f[4] * inv, f[5] * inv, 0, false);
  d1 = __builtin_amdgcn_cvt_pk_fp8_f32(f[6] * inv, f[7] * inv, d1, true);
  const int grp = t >> 3, pc = t & 7;
  unsigned char* dst = P8 + row * 2048 + grp * 64 + (pc & 3) * 16 + (pc >> 2) * 8;
  *(unsigned long long*)dst =
      (unsigned long long)d0 | ((unsigned long long)d1 << 32);
}

// =====================================================================
// g8fp8_k: 256x128xBK64 fp8 MFMA GEMM, triple-buffered (pv8 core, R16-
// validated).  A8 [.][G(k)], B8 [.][G(k)], both k-interleaved.
// EPI 1: bf16 out * scale (QK^T);  EPI 2: f32 out * scale + X (PV+res).
// =====================================================================

template<int EPI>
__global__ __launch_bounds__(512, 4) void g8fp8_k(
    const unsigned char* __restrict__ A8, const unsigned char* __restrict__ B8,
    void* __restrict__ Cv, const float* __restrict__ X,
    int K, int ldaB, int ldbB, int ldc,
    long long strA, long long strB, long long strC, long long strX, float scale) {
  __shared__ __align__(16) char Ls[73728];   // 3 bufs x (A 16KB + B 8KB)

  const int lane = threadIdx.x & 63;
  const int w = threadIdx.x >> 6;
  const int wm = w >> 1, wn = w & 1;
  const int l15 = lane & 15;
  const int g4 = lane >> 4;
  const int swB = ((g4 ^ ((l15 >> 1) & 3)) << 4);   // byte slot offset
  const int arow = (wm * 64 + l15) * 64 + swB;
  const int brow = (wn * 64 + l15) * 64 + swB;
  const int sg = (lane & 3) ^ ((lane >> 3) & 3);

  const int gx = gridDim.x, gy = gridDim.y;
  const int nwg = gx * gy * gridDim.z;
  int lid = blockIdx.x + gx * (blockIdx.y + gy * blockIdx.z);
  lid = (lid & 7) * (nwg >> 3) + (lid >> 3);
  const int bx = lid % gx;
  const int rem = lid / gx;
  const int by = rem % gy;
  const int bz = rem / gy;
  const int n0 = bx * 128, m0 = by * 256;
  const int nt = K >> 6;

  const long long ldaL = ldaB, ldbL = ldbB;
  const char* pA = (const char*)A8 + bz * strA
      + (long long)(m0 + w * 32 + (lane >> 2)) * ldaL + sg * 16;
  const char* pB = (const char*)B8 + bz * strB
      + (long long)(n0 + w * 16 + (lane >> 2)) * ldbL + sg * 16;
  const long long ldaL16 = 16 * ldaL;

  char* dA = Ls + w * 2048;             // + buf*24576
  char* dB = Ls + 16384 + w * 1024;     // + buf*24576

  f32x4 acc[4][4] = {};

#pragma unroll
  for (int i = 0; i < 3; ++i) {
    const char* qA = pA + i * 64;
    gload16(qA,           dA + i * 24576);
    gload16(qA + ldaL16,  dA + i * 24576 + 1024);
    gload16(pB + i * 64,  dB + i * 24576);
  }
  asm volatile("s_waitcnt vmcnt(6)" ::: "memory");
  __builtin_amdgcn_s_barrier();

  int cur = 0;
  for (int t = 0; t < nt; ++t) {
    const int bufO = cur * 24576;
    i64x2 aA[4], bB[4];
#pragma unroll
    for (int mi = 0; mi < 4; ++mi)
      aA[mi] = *(const i64x2*)(Ls + bufO + arow + mi * 1024);
#pragma unroll
    for (int ni = 0; ni < 4; ++ni)
      bB[ni] = *(const i64x2*)(Ls + bufO + 16384 + brow + ni * 1024);
    asm volatile("s_waitcnt lgkmcnt(0)" ::: "memory");
    __builtin_amdgcn_s_barrier();
    if (t + 3 < nt) {
      const char* qA = pA + (t + 3) * 64;
      gload16(qA,          dA + bufO);
      gload16(qA + ldaL16, dA + bufO + 1024);
      gload16(pB + (t + 3) * 64, dB + bufO);
    }
    __builtin_amdgcn_sched_barrier(0);
    __builtin_amdgcn_s_setprio(1);
#pragma unroll
    for (int mi = 0; mi < 4; ++mi)
#pragma unroll
      for (int ni = 0; ni < 4; ++ni) {
        acc[mi][ni] = __builtin_amdgcn_mfma_f32_16x16x32_fp8_fp8(
            aA[mi][0], bB[ni][0], acc[mi][ni], 0, 0, 0);
        acc[mi][ni] = __builtin_amdgcn_mfma_f32_16x16x32_fp8_fp8(
            aA[mi][1], bB[ni][1], acc[mi][ni], 0, 0, 0);
      }
    __builtin_amdgcn_s_setprio(0);
    if (t + 3 < nt)      asm volatile("s_waitcnt vmcnt(6)" ::: "memory");
    else if (t + 2 < nt) asm volatile("s_waitcnt vmcnt(3)" ::: "memory");
    else                 asm volatile("s_waitcnt vmcnt(0)" ::: "memory");
    __builtin_amdgcn_s_barrier();
    cur = (cur == 2) ? 0 : cur + 1;
  }

  const int rB = g4 * 4;
  if (EPI == 1) {
    short* C = (short*)Cv + bz * strC;
#pragma unroll
    for (int ni = 0; ni < 4; ++ni) {
      const int col = n0 + wn * 64 + ni * 16 + l15;
#pragma unroll
      for (int mi = 0; mi < 4; ++mi)
#pragma unroll
        for (int r = 0; r < 4; ++r) {
          const int row = m0 + wm * 64 + mi * 16 + rB + r;
          C[(long long)row * ldc + col] = f2bf(acc[mi][ni][r] * scale);
        }
    }
  } else {  // EPI == 2
    float* C = (float*)Cv + bz * strC;
    const float* Xb = X + bz * strX;
#pragma unroll
    for (int ni = 0; ni < 4; ++ni) {
      const int col = n0 + wn * 64 + ni * 16 + l15;
#pragma unroll
      for (int mi = 0; mi < 4; ++mi)
#pragma unroll
        for (int r = 0; r < 4; ++r) {
          const int row = m0 + wm * 64 + mi * 16 + rB + r;
          const long long idx = (long long)row * ldc + col;
          C[idx] = acc[mi][ni][r] * scale + Xb[idx];
        }
    }
  }
}

extern "C" void kernel_launch(void* const* d_in, const int* in_sizes, int n_in,
                              void* d_out, int out_size, void* d_ws, size_t ws_size,
                              hipStream_t stream) {
  const float* x  = (const float*)d_in[0];
  const float* y  = (const float*)d_in[1];
  const float* Wq = (const float*)d_in[2];
  const float* bq = (const float*)d_in[3];
  const float* Wk = (const float*)d_in[4];
  const float* bk = (const float*)d_in[5];
  const float* Wv = (const float*)d_in[6];
  const float* bv = (const float*)d_in[7];
  float* out = (float*)d_out;

  const long long SD  = 2048LL * 1024;
  const long long BSD = 16LL * SD;
  const long long SS  = 2048LL * 2048;

  char* ws = (char*)d_ws;
  short* xb  = (short*)ws;                   // 67.1 MB
  short* yb  = xb + BSD;                     // 67.1 MB
  short* Sl  = (short*)ws;                   // 134.2 MB (aliases xb+yb)
  unsigned char* Q8 = (unsigned char*)(ws + 134217728);  // 33.5 MB fp8
  unsigned char* P8 = Q8;                    // 67.1 MB fp8 (reuses Q8 region)
  unsigned char* K8 = (unsigned char*)(ws + 201326592);  // 33.5 MB fp8
  unsigned char* V8 = (unsigned char*)(ws + 268435456);  // 33.5 MB fp8
  short* Wqt = (short*)(ws + 335544320);     // 2 MB each
  short* Wkt = Wqt + 1024 * 1024;
  short* Wvt = Wkt + 1024 * 1024;

  // 1) convert x, y to bf16
  cvt_k<<<2048, 256, 0, stream>>>(x, xb, (int)(BSD / 4));
  cvt_k<<<2048, 256, 0, stream>>>(y, yb, (int)(BSD / 4));

  // 2) transpose+convert weights
  cvtT_k<<<dim3(32, 32), 256, 0, stream>>>(Wq, Wqt);
  cvtT_k<<<dim3(32, 32), 256, 0, stream>>>(Wk, Wkt);
  cvtT_k<<<dim3(32, 32), 256, 0, stream>>>(Wv, Wvt);

  // 3) Q8 = e4m3(xb @ Wq + bq), k-interleaved over d
  gemm256_k<4><<<dim3(4, 128, 1), 512, 0, stream>>>(
      xb, Wqt, Q8, bq, 1024, 1024, 1024, 1024);
  // 4) K8 = e4m3(yb @ Wk + bk)
  gemm256_k<4><<<dim3(4, 128, 1), 512, 0, stream>>>(
      yb, Wkt, K8, bk, 1024, 1024, 1024, 1024);
  // 5) V8 = e4m3(V^T): A = Wv^T, Bt = yb -> [b][f][G(s)]
  gemm256_k<3><<<dim3(128, 4, 1), 512, 0, stream>>>(
      Wvt, yb, V8, bv, 1024, 1024, 1024, 0);

  // 6) logits = (Q8 @ K8^T) / 32 -> Sl bf16   (fp8 GEMM, K=1024)
  g8fp8_k<1><<<dim3(16, 8, 16), 512, 0, stream>>>(
      Q8, K8, Sl, nullptr, 1024, 1024, 1024, 2048,
      2097152LL, 2097152LL, SS, 0, 0.03125f);

  // 7) softmax rows -> P8 = e4m3(256 * P), k-interleaved (overwrites Q8)
  softmax8_k<<<32768, 256, 0, stream>>>(Sl, P8);

  // 8) out = (P8 @ V8) / 256 + x   (fp8 GEMM, K=2048)
  g8fp8_k<2><<<dim3(8, 8, 16), 512, 0, stream>>>(
      P8, V8, out, x, 2048, 2048, 2048, 1024,
      4194304LL, 2097152LL, SD, SD, 0.00390625f);

  (void)in_sizes; (void)n_in; (void)out_size; (void)ws_size;
}

// Round 18
// 610.624 us; speedup vs baseline: 2.4351x; 1.0094x over previous
//
#include <hip/hip_runtime.h>
#include <hip/hip_bf16.h>

typedef __attribute__((ext_vector_type(8))) short bf16x8;
typedef __attribute__((ext_vector_type(4))) float f32x4;
typedef __attribute__((ext_vector_type(2))) long i64x2;

__device__ __forceinline__ float bf2f(short u) {
  union { unsigned int u; float f; } c;
  c.u = ((unsigned int)(unsigned short)u) << 16;
  return c.f;
}
__device__ __forceinline__ short f2bf(float f) {
  union { float f; unsigned int u; } c; c.f = f;
  unsigned int r = (c.u + 0x7fffu + ((c.u >> 16) & 1u)) >> 16;
  return (short)(unsigned short)r;
}

// exact e4m3fn -> f32 decode (bit trick; subnormals exact; no NaN inputs)
__device__ __forceinline__ float fp8_dec(unsigned b) {
  union { unsigned u; float f; } c;
  c.u = (b & 0x7fu) << 20;
  float v = c.f * 1.329227995784916e+36f;   // 2^120
  return (b & 0x80u) ? -v : v;
}

__device__ __forceinline__ void gload16(const void* g, void* l) {
  __builtin_amdgcn_global_load_lds(
      (const __attribute__((address_space(1))) unsigned int*)g,
      (__attribute__((address_space(3))) unsigned int*)l, 16, 0, 0);
}

// fp8 interleave within a 64-k group: logical k -> stored byte
__device__ __forceinline__ int fp8_g(int s) {
  return (s >> 6) * 64 + ((s >> 3) & 3) * 16 + ((s >> 5) & 1) * 8 + (s & 7);
}

// ---------------- fp32 -> bf16 convert ----------------
__global__ __launch_bounds__(256) void cvt_k(const float* __restrict__ in,
                                             short* __restrict__ out, int n4) {
  int i = blockIdx.x * blockDim.x + threadIdx.x;
  const int stride = gridDim.x * blockDim.x;
  for (; i < n4; i += stride) {
    float4 v = ((const float4*)in)[i];
    short4 o;
    o.x = f2bf(v.x); o.y = f2bf(v.y); o.z = f2bf(v.z); o.w = f2bf(v.w);
    ((short4*)out)[i] = o;
  }
}

// ---------------- W [1024][1024] f32 -> W^T bf16 ----------------
__global__ __launch_bounds__(256) void cvtT_k(const float* __restrict__ W,
                                              short* __restrict__ Wt) {
  __shared__ float tile[32][33];
  const int n0 = blockIdx.x * 32, k0 = blockIdx.y * 32;
  const int tr = threadIdx.x >> 5;
  const int tc = threadIdx.x & 31;
#pragma unroll
  for (int p = 0; p < 4; ++p)
    tile[p * 8 + tr][tc] = W[(long long)(k0 + p * 8 + tr) * 1024 + n0 + tc];
  __syncthreads();
#pragma unroll
  for (int p = 0; p < 4; ++p)
    Wt[(long long)(n0 + p * 8 + tr) * 1024 + k0 + tc] = f2bf(tile[tc][p * 8 + tr]);
}

// =====================================================================
// gemm256_k: 256x256x64 8-phase bf16 MFMA GEMM (R6 core, validated)
// EPI 3: V^T fp8-e4m3 [b][f][G(s)], +bias[row].
// EPI 4: fp8-e4m3 row-major [row][G(col)], +bias[col]  (Q/K projections).
// =====================================================================

#define STG6(sp, ld8, dOff) do { \
  gload16((sp), Ls + (dOff)); \
  gload16((const char*)(sp) + (ld8), Ls + (dOff) + 512); } while (0)

#define RD_A6(BUF, QM) do { \
  _Pragma("unroll") \
  for (int mi = 0; mi < 4; ++mi) { \
    aR[mi][0] = *(const bf16x8*)(Ls + (BUF) + (QM)*8192 + arow + mi*1024 + aO0); \
    aR[mi][1] = *(const bf16x8*)(Ls + (BUF) + (QM)*8192 + arow + mi*1024 + aO1); \
  } } while (0)

#define RD_B6(DST, BUF, QN) do { \
  _Pragma("unroll") \
  for (int ni = 0; ni < 2; ++ni) { \
    DST[ni][0] = *(const bf16x8*)(Ls + (BUF) + 16384 + (QN)*8192 + brow + ni*1024 + aO0); \
    DST[ni][1] = *(const bf16x8*)(Ls + (BUF) + 16384 + (QN)*8192 + brow + ni*1024 + aO1); \
  } } while (0)

#define SYNCIN6 do { \
  __builtin_amdgcn_sched_barrier(0); \
  __builtin_amdgcn_s_barrier(); \
  asm volatile("s_waitcnt lgkmcnt(0)" ::: "memory"); \
  __builtin_amdgcn_sched_barrier(0); \
  __builtin_amdgcn_s_setprio(1); } while (0)

#define SYNCOUT6 do { \
  __builtin_amdgcn_s_setprio(0); \
  __builtin_amdgcn_s_barrier(); } while (0)

#define MF166(ACCQ, BB) do { \
  _Pragma("unroll") \
  for (int mi = 0; mi < 4; ++mi) { \
    _Pragma("unroll") \
    for (int ni = 0; ni < 2; ++ni) { \
      ACCQ[mi][ni] = __builtin_amdgcn_mfma_f32_16x16x32_bf16(aR[mi][0], BB[ni][0], ACCQ[mi][ni], 0, 0, 0); \
      ACCQ[mi][ni] = __builtin_amdgcn_mfma_f32_16x16x32_bf16(aR[mi][1], BB[ni][1], ACCQ[mi][ni], 0, 0, 0); \
    } \
  } } while (0)

template<int EPI>
__global__ __launch_bounds__(512) void gemm256_k(
    const short* __restrict__ A, const short* __restrict__ Bt,
    void* __restrict__ Cv, const float* __restrict__ X,
    int K, int lda, int ldb, int ldc) {
  __shared__ __align__(16) short Ls[65536];   // 128 KiB

  const int lane = threadIdx.x & 63;
  const int w = threadIdx.x >> 6;
  const int wm = w >> 2, wn = w & 3;
  const int w1k = w * 1024;
  const int l15 = lane & 15;
  const int g4 = lane >> 4;
  const int p8 = lane & 7;
  const int r8 = lane >> 3;
  const int aO0 = (g4 ^ p8) << 3;
  const int aO1 = ((4 + g4) ^ p8) << 3;
  const int arow = (wm * 64 + l15) * 64;
  const int brow = (wn * 32 + l15) * 64;

  const int gx = gridDim.x, gy = gridDim.y;
  const int nwg = gx * gy * gridDim.z;
  int lid = blockIdx.x + gx * (blockIdx.y + gy * blockIdx.z);
  lid = (lid & 7) * (nwg >> 3) + (lid >> 3);
  const int bx = lid % gx;
  const int rem = lid / gx;
  const int by = rem % gy;

  const int n0 = bx * 256;
  const int m0 = by * 256;
  const int nt = K >> 6;
  const int nit = nt >> 1;

  const long long ldaB = 2LL * lda, ldbB = 2LL * ldb;
  const long long ldaB8 = 8 * ldaB, ldbB8 = 8 * ldbB;
  const long long hOffA = 128 * ldaB, hOffB = 128 * ldbB;

  const char* pA = (const char*)A
      + (long long)(m0 + w * 16 + r8) * ldaB + ((p8 ^ r8) << 4);
  const char* pB = (const char*)Bt
      + (long long)(n0 + w * 16 + r8) * ldbB + ((p8 ^ r8) << 4);

  f32x4 acc[2][2][4][2] = {};
  bf16x8 aR[4][2], bR0[2][2], bR1[2][2];

  STG6(pA,                 ldaB8, 0 + w1k);
  STG6(pA + hOffA,         ldaB8, 8192 + w1k);
  STG6(pB,                 ldbB8, 16384 + w1k);
  STG6(pB + hOffB,         ldbB8, 24576 + w1k);
  STG6(pA + 128,           ldaB8, 32768 + w1k);
  STG6(pA + 128 + hOffA,   ldaB8, 40960 + w1k);
  STG6(pB + 128,           ldbB8, 49152 + w1k);
  STG6(pB + 128 + hOffB,   ldbB8, 57344 + w1k);
  asm volatile("s_waitcnt vmcnt(8)" ::: "memory");
  __builtin_amdgcn_s_barrier();

  for (int j = 0; j < nit; ++j) {
    const bool st = (j + 1 < nit);

    RD_A6(0, 0); RD_B6(bR0, 0, 0);
    SYNCIN6; MF166(acc[0][0], bR0); SYNCOUT6;
    RD_B6(bR1, 0, 1);
    if (st) { STG6(pA + 256, ldaB8, 0 + w1k);
              STG6(pB + 256, ldbB8, 16384 + w1k); }
    SYNCIN6; MF166(acc[0][1], bR1); SYNCOUT6;
    RD_A6(0, 1);
    if (st) STG6(pB + 256 + hOffB, ldbB8, 24576 + w1k);
    SYNCIN6; MF166(acc[1][1], bR1); SYNCOUT6;
    if (st) STG6(pA + 256 + hOffA, ldaB8, 8192 + w1k);
    SYNCIN6; MF166(acc[1][0], bR0);
    __builtin_amdgcn_s_setprio(0);
    if (st) asm volatile("s_waitcnt vmcnt(8)" ::: "memory");
    else    asm volatile("s_waitcnt vmcnt(0)" ::: "memory");
    __builtin_amdgcn_s_barrier();

    RD_A6(32768, 0); RD_B6(bR0, 32768, 0);
    SYNCIN6; MF166(acc[0][0], bR0); SYNCOUT6;
    RD_B6(bR1, 32768, 1);
    if (st) { STG6(pA + 384, ldaB8, 32768 + w1k);
              STG6(pB + 384, ldbB8, 49152 + w1k); }
    SYNCIN6; MF166(acc[0][1], bR1); SYNCOUT6;
    RD_A6(32768, 1);
    if (st) STG6(pB + 384 + hOffB, ldbB8, 57344 + w1k);
    SYNCIN6; MF166(acc[1][1], bR1); SYNCOUT6;
    if (st) STG6(pA + 384 + hOffA, ldaB8, 40960 + w1k);
    SYNCIN6; MF166(acc[1][0], bR0);
    __builtin_amdgcn_s_setprio(0);
    if (st) asm volatile("s_waitcnt vmcnt(8)" ::: "memory");
    __builtin_amdgcn_s_barrier();

    pA += 256; pB += 256;
  }

  const int rB = g4 * 4;
  if (EPI == 3) {  // V^T fp8, [b][f=row][G(s)], n = b*2048 + s
    unsigned char* C = (unsigned char*)Cv;
#pragma unroll
    for (int qn = 0; qn < 2; ++qn)
#pragma unroll
      for (int ni = 0; ni < 2; ++ni) {
        const int col = n0 + qn * 128 + wn * 32 + ni * 16 + l15;
        const int b2 = col >> 11;
        const int s = col & 2047;
        const int gs = fp8_g(s);
#pragma unroll
        for (int qm = 0; qm < 2; ++qm)
#pragma unroll
          for (int mi = 0; mi < 4; ++mi)
#pragma unroll
            for (int r = 0; r < 4; ++r) {
              const int row = m0 + qm * 128 + wm * 64 + mi * 16 + rB + r;
              const float v = acc[qm][qn][mi][ni][r] + X[row];
              const unsigned d = __builtin_amdgcn_cvt_pk_fp8_f32(v, v, 0, false);
              C[(long long)b2 * 2097152 + (long long)row * 2048 + gs] =
                  (unsigned char)(d & 0xff);
            }
      }
  } else {  // EPI == 4: fp8 row-major [row][G(col)], +bias[col]
    unsigned char* C = (unsigned char*)Cv;
#pragma unroll
    for (int qn = 0; qn < 2; ++qn)
#pragma unroll
      for (int ni = 0; ni < 2; ++ni) {
        const int col = n0 + qn * 128 + wn * 32 + ni * 16 + l15;
        const int gs = fp8_g(col);
        const float bv = X[col];
#pragma unroll
        for (int qm = 0; qm < 2; ++qm)
#pragma unroll
          for (int mi = 0; mi < 4; ++mi)
#pragma unroll
            for (int r = 0; r < 4; ++r) {
              const int row = m0 + qm * 128 + wm * 64 + mi * 16 + rB + r;
              const float v = acc[qm][qn][mi][ni][r] + bv;
              const unsigned d = __builtin_amdgcn_cvt_pk_fp8_f32(v, v, 0, false);
              C[(long long)row * ldc + gs] = (unsigned char)(d & 0xff);
            }
      }
  }
}

// ---------- row softmax over 2048: fp8 logits in -> fp8 P (x256, interleaved) ----------
__global__ __launch_bounds__(256) void softmax8_k(const unsigned char* __restrict__ Sl8,
                                                  unsigned char* __restrict__ P8) {
  __shared__ float redm[4];
  __shared__ float reds[4];
  const long long row = blockIdx.x;
  const unsigned char* p = Sl8 + row * 2048;
  const int t = threadIdx.x;
  const int w = t >> 6, lane = t & 63;
  const unsigned long long v8 = *(const unsigned long long*)(p + t * 8);
  float f[8];
  float mx = -3.0e38f;
#pragma unroll
  for (int j = 0; j < 8; ++j) {
    f[j] = fp8_dec((unsigned)(v8 >> (8 * j)) & 0xffu);
    mx = fmaxf(mx, f[j]);
  }
#pragma unroll
  for (int o = 32; o > 0; o >>= 1) mx = fmaxf(mx, __shfl_xor(mx, o));
  if (lane == 0) redm[w] = mx;
  __syncthreads();
  mx = fmaxf(fmaxf(redm[0], redm[1]), fmaxf(redm[2], redm[3]));
  float s = 0.f;
#pragma unroll
  for (int j = 0; j < 8; ++j) { f[j] = __expf(f[j] - mx); s += f[j]; }
#pragma unroll
  for (int o = 32; o > 0; o >>= 1) s += __shfl_xor(s, o);
  if (lane == 0) reds[w] = s;
  __syncthreads();
  s = reds[0] + reds[1] + reds[2] + reds[3];
  const float inv = 256.0f / (s + 1e-6f);   // P' = 256 * P (e4m3 range fit)
  unsigned d0 = __builtin_amdgcn_cvt_pk_fp8_f32(f[0] * inv, f[1] * inv, 0, false);
  d0 = __builtin_amdgcn_cvt_pk_fp8_f32(f[2] * inv, f[3] * inv, d0, true);
  unsigned d1 = __builtin_amdgcn_cvt_pk_fp8_f32(f[4] * inv, f[5] * inv, 0, false);
  d1 = __builtin_amdgcn_cvt_pk_fp8_f32(f[6] * inv, f[7] * inv, d1, true);
  const int grp = t >> 3, pc = t & 7;
  unsigned char* dst = P8 + row * 2048 + grp * 64 + (pc & 3) * 16 + (pc >> 2) * 8;
  *(unsigned long long*)dst =
      (unsigned long long)d0 | ((unsigned long long)d1 << 32);
}

// =====================================================================
// g8fp8_k: 256x128xBK64 fp8 MFMA GEMM, triple-buffered (R16 core).
// EPI 1: fp8-e4m3 out (scale applied pre-convert) -> Sl8 (QK^T);
// EPI 2: f32 out * scale + X (PV + residual).
// =====================================================================

template<int EPI>
__global__ __launch_bounds__(512, 4) void g8fp8_k(
    const unsigned char* __restrict__ A8, const unsigned char* __restrict__ B8,
    void* __restrict__ Cv, const float* __restrict__ X,
    int K, int ldaB, int ldbB, int ldc,
    long long strA, long long strB, long long strC, long long strX, float scale) {
  __shared__ __align__(16) char Ls[73728];   // 3 bufs x (A 16KB + B 8KB)

  const int lane = threadIdx.x & 63;
  const int w = threadIdx.x >> 6;
  const int wm = w >> 1, wn = w & 1;
  const int l15 = lane & 15;
  const int g4 = lane >> 4;
  const int swB = ((g4 ^ ((l15 >> 1) & 3)) << 4);   // byte slot offset
  const int arow = (wm * 64 + l15) * 64 + swB;
  const int brow = (wn * 64 + l15) * 64 + swB;
  const int sg = (lane & 3) ^ ((lane >> 3) & 3);

  const int gx = gridDim.x, gy = gridDim.y;
  const int nwg = gx * gy * gridDim.z;
  int lid = blockIdx.x + gx * (blockIdx.y + gy * blockIdx.z);
  lid = (lid & 7) * (nwg >> 3) + (lid >> 3);
  const int bx = lid % gx;
  const int rem = lid / gx;
  const int by = rem % gy;
  const int bz = rem / gy;
  const int n0 = bx * 128, m0 = by * 256;
  const int nt = K >> 6;

  const long long ldaL = ldaB, ldbL = ldbB;
  const char* pA = (const char*)A8 + bz * strA
      + (long long)(m0 + w * 32 + (lane >> 2)) * ldaL + sg * 16;
  const char* pB = (const char*)B8 + bz * strB
      + (long long)(n0 + w * 16 + (lane >> 2)) * ldbL + sg * 16;
  const long long ldaL16 = 16 * ldaL;

  char* dA = Ls + w * 2048;             // + buf*24576
  char* dB = Ls + 16384 + w * 1024;     // + buf*24576

  f32x4 acc[4][4] = {};

#pragma unroll
  for (int i = 0; i < 3; ++i) {
    const char* qA = pA + i * 64;
    gload16(qA,           dA + i * 24576);
    gload16(qA + ldaL16,  dA + i * 24576 + 1024);
    gload16(pB + i * 64,  dB + i * 24576);
  }
  asm volatile("s_waitcnt vmcnt(6)" ::: "memory");
  __builtin_amdgcn_s_barrier();

  int cur = 0;
  for (int t = 0; t < nt; ++t) {
    const int bufO = cur * 24576;
    i64x2 aA[4], bB[4];
#pragma unroll
    for (int mi = 0; mi < 4; ++mi)
      aA[mi] = *(const i64x2*)(Ls + bufO + arow + mi * 1024);
#pragma unroll
    for (int ni = 0; ni < 4; ++ni)
      bB[ni] = *(const i64x2*)(Ls + bufO + 16384 + brow + ni * 1024);
    asm volatile("s_waitcnt lgkmcnt(0)" ::: "memory");
    __builtin_amdgcn_s_barrier();
    if (t + 3 < nt) {
      const char* qA = pA + (t + 3) * 64;
      gload16(qA,          dA + bufO);
      gload16(qA + ldaL16, dA + bufO + 1024);
      gload16(pB + (t + 3) * 64, dB + bufO);
    }
    __builtin_amdgcn_sched_barrier(0);
    __builtin_amdgcn_s_setprio(1);
#pragma unroll
    for (int mi = 0; mi < 4; ++mi)
#pragma unroll
      for (int ni = 0; ni < 4; ++ni) {
        acc[mi][ni] = __builtin_amdgcn_mfma_f32_16x16x32_fp8_fp8(
            aA[mi][0], bB[ni][0], acc[mi][ni], 0, 0, 0);
        acc[mi][ni] = __builtin_amdgcn_mfma_f32_16x16x32_fp8_fp8(
            aA[mi][1], bB[ni][1], acc[mi][ni], 0, 0, 0);
      }
    __builtin_amdgcn_s_setprio(0);
    if (t + 3 < nt)      asm volatile("s_waitcnt vmcnt(6)" ::: "memory");
    else if (t + 2 < nt) asm volatile("s_waitcnt vmcnt(3)" ::: "memory");
    else                 asm volatile("s_waitcnt vmcnt(0)" ::: "memory");
    __builtin_amdgcn_s_barrier();
    cur = (cur == 2) ? 0 : cur + 1;
  }

  const int rB = g4 * 4;
  if (EPI == 1) {  // Sl8 = e4m3(acc * scale), row-major bytes
    unsigned char* C = (unsigned char*)Cv + bz * strC;
#pragma unroll
    for (int ni = 0; ni < 4; ++ni) {
      const int col = n0 + wn * 64 + ni * 16 + l15;
#pragma unroll
      for (int mi = 0; mi < 4; ++mi)
#pragma unroll
        for (int r = 0; r < 4; ++r) {
          const int row = m0 + wm * 64 + mi * 16 + rB + r;
          const float v = acc[mi][ni][r] * scale;
          const unsigned d = __builtin_amdgcn_cvt_pk_fp8_f32(v, v, 0, false);
          C[(long long)row * ldc + col] = (unsigned char)(d & 0xff);
        }
    }
  } else {  // EPI == 2
    float* C = (float*)Cv + bz * strC;
    const float* Xb = X + bz * strX;
#pragma unroll
    for (int ni = 0; ni < 4; ++ni) {
      const int col = n0 + wn * 64 + ni * 16 + l15;
#pragma unroll
      for (int mi = 0; mi < 4; ++mi)
#pragma unroll
        for (int r = 0; r < 4; ++r) {
          const int row = m0 + wm * 64 + mi * 16 + rB + r;
          const long long idx = (long long)row * ldc + col;
          C[idx] = acc[mi][ni][r] * scale + Xb[idx];
        }
    }
  }
}

extern "C" void kernel_launch(void* const* d_in, const int* in_sizes, int n_in,
                              void* d_out, int out_size, void* d_ws, size_t ws_size,
                              hipStream_t stream) {
  const float* x  = (const float*)d_in[0];
  const float* y  = (const float*)d_in[1];
  const float* Wq = (const float*)d_in[2];
  const float* bq = (const float*)d_in[3];
  const float* Wk = (const float*)d_in[4];
  const float* bk = (const float*)d_in[5];
  const float* Wv = (const float*)d_in[6];
  const float* bv = (const float*)d_in[7];
  float* out = (float*)d_out;

  const long long SD  = 2048LL * 1024;
  const long long BSD = 16LL * SD;
  const long long SS  = 2048LL * 2048;

  char* ws = (char*)d_ws;
  short* xb  = (short*)ws;                   // 67.1 MB
  short* yb  = xb + BSD;                     // 67.1 MB
  unsigned char* Sl8 = (unsigned char*)ws;   // 67.1 MB fp8 (aliases xb; dead then)
  unsigned char* Q8 = (unsigned char*)(ws + 134217728);  // 33.5 MB fp8
  unsigned char* P8 = Q8;                    // 67.1 MB fp8 (reuses Q8 region)
  unsigned char* K8 = (unsigned char*)(ws + 201326592);  // 33.5 MB fp8
  unsigned char* V8 = (unsigned char*)(ws + 268435456);  // 33.5 MB fp8
  short* Wqt = (short*)(ws + 335544320);     // 2 MB each
  short* Wkt = Wqt + 1024 * 1024;
  short* Wvt = Wkt + 1024 * 1024;

  // 1) convert x, y to bf16
  cvt_k<<<2048, 256, 0, stream>>>(x, xb, (int)(BSD / 4));
  cvt_k<<<2048, 256, 0, stream>>>(y, yb, (int)(BSD / 4));

  // 2) transpose+convert weights
  cvtT_k<<<dim3(32, 32), 256, 0, stream>>>(Wq, Wqt);
  cvtT_k<<<dim3(32, 32), 256, 0, stream>>>(Wk, Wkt);
  cvtT_k<<<dim3(32, 32), 256, 0, stream>>>(Wv, Wvt);

  // 3) Q8 = e4m3(xb @ Wq + bq), k-interleaved over d
  gemm256_k<4><<<dim3(4, 128, 1), 512, 0, stream>>>(
      xb, Wqt, Q8, bq, 1024, 1024, 1024, 1024);
  // 4) K8 = e4m3(yb @ Wk + bk)
  gemm256_k<4><<<dim3(4, 128, 1), 512, 0, stream>>>(
      yb, Wkt, K8, bk, 1024, 1024, 1024, 1024);
  // 5) V8 = e4m3(V^T): A = Wv^T, Bt = yb -> [b][f][G(s)]
  gemm256_k<3><<<dim3(128, 4, 1), 512, 0, stream>>>(
      Wvt, yb, V8, bv, 1024, 1024, 1024, 0);

  // 6) Sl8 = e4m3((Q8 @ K8^T)/32)   (fp8 GEMM, K=1024; overwrites xb region)
  g8fp8_k<1><<<dim3(16, 8, 16), 512, 0, stream>>>(
      Q8, K8, Sl8, nullptr, 1024, 1024, 1024, 2048,
      2097152LL, 2097152LL, SS, 0, 0.03125f);

  // 7) softmax rows (fp8 in) -> P8 = e4m3(256 * P), k-interleaved
  softmax8_k<<<32768, 256, 0, stream>>>(Sl8, P8);

  // 8) out = (P8 @ V8) / 256 + x   (fp8 GEMM, K=2048)
  g8fp8_k<2><<<dim3(8, 8, 16), 512, 0, stream>>>(
      P8, V8, out, x, 2048, 2048, 2048, 1024,
      4194304LL, 2097152LL, SD, SD, 0.00390625f);

  (void)in_sizes; (void)n_in; (void)out_size; (void)ws_size;
}

// Round 19
// 603.190 us; speedup vs baseline: 2.4651x; 1.0123x over previous
//
#include <hip/hip_runtime.h>
#include <hip/hip_bf16.h>

typedef __attribute__((ext_vector_type(8))) short bf16x8;
typedef __attribute__((ext_vector_type(4))) float f32x4;
typedef __attribute__((ext_vector_type(2))) long i64x2;

__device__ __forceinline__ float bf2f(short u) {
  union { unsigned int u; float f; } c;
  c.u = ((unsigned int)(unsigned short)u) << 16;
  return c.f;
}
__device__ __forceinline__ short f2bf(float f) {
  union { float f; unsigned int u; } c; c.f = f;
  unsigned int r = (c.u + 0x7fffu + ((c.u >> 16) & 1u)) >> 16;
  return (short)(unsigned short)r;
}

// exact e4m3fn -> f32 decode (bit trick; subnormals exact; no NaN inputs)
__device__ __forceinline__ float fp8_dec(unsigned b) {
  union { unsigned u; float f; } c;
  c.u = (b & 0x7fu) << 20;
  float v = c.f * 1.329227995784916e+36f;   // 2^120
  return (b & 0x80u) ? -v : v;
}

__device__ __forceinline__ void gload16(const void* g, void* l) {
  __builtin_amdgcn_global_load_lds(
      (const __attribute__((address_space(1))) unsigned int*)g,
      (__attribute__((address_space(3))) unsigned int*)l, 16, 0, 0);
}

// fp8 interleave within a 64-k group: logical k -> stored byte
__device__ __forceinline__ int fp8_g(int s) {
  return (s >> 6) * 64 + ((s >> 3) & 3) * 16 + ((s >> 5) & 1) * 8 + (s & 7);
}

// ---------------- fp32 -> bf16 convert (x and y in one dispatch) ----------------
__global__ __launch_bounds__(256) void cvt2_k(const float* __restrict__ x,
                                              const float* __restrict__ y,
                                              short* __restrict__ xb,
                                              short* __restrict__ yb, int n4) {
  const float* in = blockIdx.z ? y : x;
  short* out = blockIdx.z ? yb : xb;
  int i = blockIdx.x * blockDim.x + threadIdx.x;
  const int stride = gridDim.x * blockDim.x;
  for (; i < n4; i += stride) {
    float4 v = ((const float4*)in)[i];
    short4 o;
    o.x = f2bf(v.x); o.y = f2bf(v.y); o.z = f2bf(v.z); o.w = f2bf(v.w);
    ((short4*)out)[i] = o;
  }
}

// ---------------- W [1024][1024] f32 -> W^T bf16 (3 weights, z-batched) ----------------
__global__ __launch_bounds__(256) void cvtT3_k(
    const float* __restrict__ Wq, const float* __restrict__ Wk,
    const float* __restrict__ Wv, short* __restrict__ Wqt,
    short* __restrict__ Wkt, short* __restrict__ Wvt) {
  const float* W = (blockIdx.z == 0) ? Wq : (blockIdx.z == 1) ? Wk : Wv;
  short* Wt = (blockIdx.z == 0) ? Wqt : (blockIdx.z == 1) ? Wkt : Wvt;
  __shared__ float tile[32][33];
  const int n0 = blockIdx.x * 32, k0 = blockIdx.y * 32;
  const int tr = threadIdx.x >> 5;
  const int tc = threadIdx.x & 31;
#pragma unroll
  for (int p = 0; p < 4; ++p)
    tile[p * 8 + tr][tc] = W[(long long)(k0 + p * 8 + tr) * 1024 + n0 + tc];
  __syncthreads();
#pragma unroll
  for (int p = 0; p < 4; ++p)
    Wt[(long long)(n0 + p * 8 + tr) * 1024 + k0 + tc] = f2bf(tile[tc][p * 8 + tr]);
}

// =====================================================================
// gemm256_k: 256x256x64 8-phase bf16 MFMA GEMM (R6 core, validated)
// Batched over z with element strides strA/strB (shorts), strC (bytes);
// bias X (z==0) or X2 (z==1).
// EPI 3: V^T fp8-e4m3 [b][f][G(s)], +bias[row].
// EPI 4: fp8-e4m3 row-major [row][G(col)], +bias[col]  (Q/K projections).
// =====================================================================

#define STG6(sp, ld8, dOff) do { \
  gload16((sp), Ls + (dOff)); \
  gload16((const char*)(sp) + (ld8), Ls + (dOff) + 512); } while (0)

#define RD_A6(BUF, QM) do { \
  _Pragma("unroll") \
  for (int mi = 0; mi < 4; ++mi) { \
    aR[mi][0] = *(const bf16x8*)(Ls + (BUF) + (QM)*8192 + arow + mi*1024 + aO0); \
    aR[mi][1] = *(const bf16x8*)(Ls + (BUF) + (QM)*8192 + arow + mi*1024 + aO1); \
  } } while (0)

#define RD_B6(DST, BUF, QN) do { \
  _Pragma("unroll") \
  for (int ni = 0; ni < 2; ++ni) { \
    DST[ni][0] = *(const bf16x8*)(Ls + (BUF) + 16384 + (QN)*8192 + brow + ni*1024 + aO0); \
    DST[ni][1] = *(const bf16x8*)(Ls + (BUF) + 16384 + (QN)*8192 + brow + ni*1024 + aO1); \
  } } while (0)

#define SYNCIN6 do { \
  __builtin_amdgcn_sched_barrier(0); \
  __builtin_amdgcn_s_barrier(); \
  asm volatile("s_waitcnt lgkmcnt(0)" ::: "memory"); \
  __builtin_amdgcn_sched_barrier(0); \
  __builtin_amdgcn_s_setprio(1); } while (0)

#define SYNCOUT6 do { \
  __builtin_amdgcn_s_setprio(0); \
  __builtin_amdgcn_s_barrier(); } while (0)

#define MF166(ACCQ, BB) do { \
  _Pragma("unroll") \
  for (int mi = 0; mi < 4; ++mi) { \
    _Pragma("unroll") \
    for (int ni = 0; ni < 2; ++ni) { \
      ACCQ[mi][ni] = __builtin_amdgcn_mfma_f32_16x16x32_bf16(aR[mi][0], BB[ni][0], ACCQ[mi][ni], 0, 0, 0); \
      ACCQ[mi][ni] = __builtin_amdgcn_mfma_f32_16x16x32_bf16(aR[mi][1], BB[ni][1], ACCQ[mi][ni], 0, 0, 0); \
    } \
  } } while (0)

template<int EPI>
__global__ __launch_bounds__(512) void gemm256_k(
    const short* __restrict__ A, const short* __restrict__ Bt,
    void* __restrict__ Cv, const float* __restrict__ X,
    const float* __restrict__ X2,
    int K, int lda, int ldb, int ldc,
    long long strA, long long strB, long long strC) {
  __shared__ __align__(16) short Ls[65536];   // 128 KiB

  const int lane = threadIdx.x & 63;
  const int w = threadIdx.x >> 6;
  const int wm = w >> 2, wn = w & 3;
  const int w1k = w * 1024;
  const int l15 = lane & 15;
  const int g4 = lane >> 4;
  const int p8 = lane & 7;
  const int r8 = lane >> 3;
  const int aO0 = (g4 ^ p8) << 3;
  const int aO1 = ((4 + g4) ^ p8) << 3;
  const int arow = (wm * 64 + l15) * 64;
  const int brow = (wn * 32 + l15) * 64;

  const int gx = gridDim.x, gy = gridDim.y;
  const int nwg = gx * gy * gridDim.z;
  int lid = blockIdx.x + gx * (blockIdx.y + gy * blockIdx.z);
  lid = (lid & 7) * (nwg >> 3) + (lid >> 3);
  const int bx = lid % gx;
  const int rem = lid / gx;
  const int by = rem % gy;
  const int bz = rem / gy;

  const int n0 = bx * 256;
  const int m0 = by * 256;
  const int nt = K >> 6;
  const int nit = nt >> 1;

  const float* Xs = bz ? X2 : X;

  const long long ldaB = 2LL * lda, ldbB = 2LL * ldb;
  const long long ldaB8 = 8 * ldaB, ldbB8 = 8 * ldbB;
  const long long hOffA = 128 * ldaB, hOffB = 128 * ldbB;

  const char* pA = (const char*)(A + bz * strA)
      + (long long)(m0 + w * 16 + r8) * ldaB + ((p8 ^ r8) << 4);
  const char* pB = (const char*)(Bt + bz * strB)
      + (long long)(n0 + w * 16 + r8) * ldbB + ((p8 ^ r8) << 4);

  f32x4 acc[2][2][4][2] = {};
  bf16x8 aR[4][2], bR0[2][2], bR1[2][2];

  STG6(pA,                 ldaB8, 0 + w1k);
  STG6(pA + hOffA,         ldaB8, 8192 + w1k);
  STG6(pB,                 ldbB8, 16384 + w1k);
  STG6(pB + hOffB,         ldbB8, 24576 + w1k);
  STG6(pA + 128,           ldaB8, 32768 + w1k);
  STG6(pA + 128 + hOffA,   ldaB8, 40960 + w1k);
  STG6(pB + 128,           ldbB8, 49152 + w1k);
  STG6(pB + 128 + hOffB,   ldbB8, 57344 + w1k);
  asm volatile("s_waitcnt vmcnt(8)" ::: "memory");
  __builtin_amdgcn_s_barrier();

  for (int j = 0; j < nit; ++j) {
    const bool st = (j + 1 < nit);

    RD_A6(0, 0); RD_B6(bR0, 0, 0);
    SYNCIN6; MF166(acc[0][0], bR0); SYNCOUT6;
    RD_B6(bR1, 0, 1);
    if (st) { STG6(pA + 256, ldaB8, 0 + w1k);
              STG6(pB + 256, ldbB8, 16384 + w1k); }
    SYNCIN6; MF166(acc[0][1], bR1); SYNCOUT6;
    RD_A6(0, 1);
    if (st) STG6(pB + 256 + hOffB, ldbB8, 24576 + w1k);
    SYNCIN6; MF166(acc[1][1], bR1); SYNCOUT6;
    if (st) STG6(pA + 256 + hOffA, ldaB8, 8192 + w1k);
    SYNCIN6; MF166(acc[1][0], bR0);
    __builtin_amdgcn_s_setprio(0);
    if (st) asm volatile("s_waitcnt vmcnt(8)" ::: "memory");
    else    asm volatile("s_waitcnt vmcnt(0)" ::: "memory");
    __builtin_amdgcn_s_barrier();

    RD_A6(32768, 0); RD_B6(bR0, 32768, 0);
    SYNCIN6; MF166(acc[0][0], bR0); SYNCOUT6;
    RD_B6(bR1, 32768, 1);
    if (st) { STG6(pA + 384, ldaB8, 32768 + w1k);
              STG6(pB + 384, ldbB8, 49152 + w1k); }
    SYNCIN6; MF166(acc[0][1], bR1); SYNCOUT6;
    RD_A6(32768, 1);
    if (st) STG6(pB + 384 + hOffB, ldbB8, 57344 + w1k);
    SYNCIN6; MF166(acc[1][1], bR1); SYNCOUT6;
    if (st) STG6(pA + 384 + hOffA, ldaB8, 40960 + w1k);
    SYNCIN6; MF166(acc[1][0], bR0);
    __builtin_amdgcn_s_setprio(0);
    if (st) asm volatile("s_waitcnt vmcnt(8)" ::: "memory");
    __builtin_amdgcn_s_barrier();

    pA += 256; pB += 256;
  }

  const int rB = g4 * 4;
  if (EPI == 3) {  // V^T fp8, [b][f=row][G(s)], n = b*2048 + s
    unsigned char* C = (unsigned char*)Cv;
#pragma unroll
    for (int qn = 0; qn < 2; ++qn)
#pragma unroll
      for (int ni = 0; ni < 2; ++ni) {
        const int col = n0 + qn * 128 + wn * 32 + ni * 16 + l15;
        const int b2 = col >> 11;
        const int s = col & 2047;
        const int gs = fp8_g(s);
#pragma unroll
        for (int qm = 0; qm < 2; ++qm)
#pragma unroll
          for (int mi = 0; mi < 4; ++mi)
#pragma unroll
            for (int r = 0; r < 4; ++r) {
              const int row = m0 + qm * 128 + wm * 64 + mi * 16 + rB + r;
              const float v = acc[qm][qn][mi][ni][r] + Xs[row];
              const unsigned d = __builtin_amdgcn_cvt_pk_fp8_f32(v, v, 0, false);
              C[(long long)b2 * 2097152 + (long long)row * 2048 + gs] =
                  (unsigned char)(d & 0xff);
            }
      }
  } else {  // EPI == 4: fp8 row-major [row][G(col)], +bias[col]
    unsigned char* C = (unsigned char*)Cv + bz * strC;
#pragma unroll
    for (int qn = 0; qn < 2; ++qn)
#pragma unroll
      for (int ni = 0; ni < 2; ++ni) {
        const int col = n0 + qn * 128 + wn * 32 + ni * 16 + l15;
        const int gs = fp8_g(col);
        const float bv = Xs[col];
#pragma unroll
        for (int qm = 0; qm < 2; ++qm)
#pragma unroll
          for (int mi = 0; mi < 4; ++mi)
#pragma unroll
            for (int r = 0; r < 4; ++r) {
              const int row = m0 + qm * 128 + wm * 64 + mi * 16 + rB + r;
              const float v = acc[qm][qn][mi][ni][r] + bv;
              const unsigned d = __builtin_amdgcn_cvt_pk_fp8_f32(v, v, 0, false);
              C[(long long)row * ldc + gs] = (unsigned char)(d & 0xff);
            }
      }
  }
}

// ---------- row softmax over 2048: fp8 logits in -> fp8 P (x256, interleaved) ----------
__global__ __launch_bounds__(256) void softmax8_k(const unsigned char* __restrict__ Sl8,
                                                  unsigned char* __restrict__ P8) {
  __shared__ float redm[4];
  __shared__ float reds[4];
  const long long row = blockIdx.x;
  const unsigned char* p = Sl8 + row * 2048;
  const int t = threadIdx.x;
  const int w = t >> 6, lane = t & 63;
  const unsigned long long v8 = *(const unsigned long long*)(p + t * 8);
  float f[8];
  float mx = -3.0e38f;
#pragma unroll
  for (int j = 0; j < 8; ++j) {
    f[j] = fp8_dec((unsigned)(v8 >> (8 * j)) & 0xffu);
    mx = fmaxf(mx, f[j]);
  }
#pragma unroll
  for (int o = 32; o > 0; o >>= 1) mx = fmaxf(mx, __shfl_xor(mx, o));
  if (lane == 0) redm[w] = mx;
  __syncthreads();
  mx = fmaxf(fmaxf(redm[0], redm[1]), fmaxf(redm[2], redm[3]));
  float s = 0.f;
#pragma unroll
  for (int j = 0; j < 8; ++j) { f[j] = __expf(f[j] - mx); s += f[j]; }
#pragma unroll
  for (int o = 32; o > 0; o >>= 1) s += __shfl_xor(s, o);
  if (lane == 0) reds[w] = s;
  __syncthreads();
  s = reds[0] + reds[1] + reds[2] + reds[3];
  const float inv = 256.0f / (s + 1e-6f);   // P' = 256 * P (e4m3 range fit)
  unsigned d0 = __builtin_amdgcn_cvt_pk_fp8_f32(f[0] * inv, f[1] * inv, 0, false);
  d0 = __builtin_amdgcn_cvt_pk_fp8_f32(f[2] * inv, f[3] * inv, d0, true);
  unsigned d1 = __builtin_amdgcn_cvt_pk_fp8_f32(f[4] * inv, f[5] * inv, 0, false);
  d1 = __builtin_amdgcn_cvt_pk_fp8_f32(f[6] * inv, f[7] * inv, d1, true);
  const int grp = t >> 3, pc = t & 7;
  unsigned char* dst = P8 + row * 2048 + grp * 64 + (pc & 3) * 16 + (pc >> 2) * 8;
  *(unsigned long long*)dst =
      (unsigned long long)d0 | ((unsigned long long)d1 << 32);
}

// =====================================================================
// g8fp8_k: 256x128xBK64 fp8 MFMA GEMM, triple-buffered (R16 core).
// EPI 1: fp8-e4m3 out (scale applied pre-convert) -> Sl8 (QK^T);
// EPI 2: f32 out * scale + X (PV + residual).
// =====================================================================

template<int EPI>
__global__ __launch_bounds__(512, 4) void g8fp8_k(
    const unsigned char* __restrict__ A8, const unsigned char* __restrict__ B8,
    void* __restrict__ Cv, const float* __restrict__ X,
    int K, int ldaB, int ldbB, int ldc,
    long long strA, long long strB, long long strC, long long strX, float scale) {
  __shared__ __align__(16) char Ls[73728];   // 3 bufs x (A 16KB + B 8KB)

  const int lane = threadIdx.x & 63;
  const int w = threadIdx.x >> 6;
  const int wm = w >> 1, wn = w & 1;
  const int l15 = lane & 15;
  const int g4 = lane >> 4;
  const int swB = ((g4 ^ ((l15 >> 1) & 3)) << 4);   // byte slot offset
  const int arow = (wm * 64 + l15) * 64 + swB;
  const int brow = (wn * 64 + l15) * 64 + swB;
  const int sg = (lane & 3) ^ ((lane >> 3) & 3);

  const int gx = gridDim.x, gy = gridDim.y;
  const int nwg = gx * gy * gridDim.z;
  int lid = blockIdx.x + gx * (blockIdx.y + gy * blockIdx.z);
  lid = (lid & 7) * (nwg >> 3) + (lid >> 3);
  const int bx = lid % gx;
  const int rem = lid / gx;
  const int by = rem % gy;
  const int bz = rem / gy;
  const int n0 = bx * 128, m0 = by * 256;
  const int nt = K >> 6;

  const long long ldaL = ldaB, ldbL = ldbB;
  const char* pA = (const char*)A8 + bz * strA
      + (long long)(m0 + w * 32 + (lane >> 2)) * ldaL + sg * 16;
  const char* pB = (const char*)B8 + bz * strB
      + (long long)(n0 + w * 16 + (lane >> 2)) * ldbL + sg * 16;
  const long long ldaL16 = 16 * ldaL;

  char* dA = Ls + w * 2048;             // + buf*24576
  char* dB = Ls + 16384 + w * 1024;     // + buf*24576

  f32x4 acc[4][4] = {};

#pragma unroll
  for (int i = 0; i < 3; ++i) {
    const char* qA = pA + i * 64;
    gload16(qA,           dA + i * 24576);
    gload16(qA + ldaL16,  dA + i * 24576 + 1024);
    gload16(pB + i * 64,  dB + i * 24576);
  }
  asm volatile("s_waitcnt vmcnt(6)" ::: "memory");
  __builtin_amdgcn_s_barrier();

  int cur = 0;
  for (int t = 0; t < nt; ++t) {
    const int bufO = cur * 24576;
    i64x2 aA[4], bB[4];
#pragma unroll
    for (int mi = 0; mi < 4; ++mi)
      aA[mi] = *(const i64x2*)(Ls + bufO + arow + mi * 1024);
#pragma unroll
    for (int ni = 0; ni < 4; ++ni)
      bB[ni] = *(const i64x2*)(Ls + bufO + 16384 + brow + ni * 1024);
    asm volatile("s_waitcnt lgkmcnt(0)" ::: "memory");
    __builtin_amdgcn_s_barrier();
    if (t + 3 < nt) {
      const char* qA = pA + (t + 3) * 64;
      gload16(qA,          dA + bufO);
      gload16(qA + ldaL16, dA + bufO + 1024);
      gload16(pB + (t + 3) * 64, dB + bufO);
    }
    __builtin_amdgcn_sched_barrier(0);
    __builtin_amdgcn_s_setprio(1);
#pragma unroll
    for (int mi = 0; mi < 4; ++mi)
#pragma unroll
      for (int ni = 0; ni < 4; ++ni) {
        acc[mi][ni] = __builtin_amdgcn_mfma_f32_16x16x32_fp8_fp8(
            aA[mi][0], bB[ni][0], acc[mi][ni], 0, 0, 0);
        acc[mi][ni] = __builtin_amdgcn_mfma_f32_16x16x32_fp8_fp8(
            aA[mi][1], bB[ni][1], acc[mi][ni], 0, 0, 0);
      }
    __builtin_amdgcn_s_setprio(0);
    if (t + 3 < nt)      asm volatile("s_waitcnt vmcnt(6)" ::: "memory");
    else if (t + 2 < nt) asm volatile("s_waitcnt vmcnt(3)" ::: "memory");
    else                 asm volatile("s_waitcnt vmcnt(0)" ::: "memory");
    __builtin_amdgcn_s_barrier();
    cur = (cur == 2) ? 0 : cur + 1;
  }

  const int rB = g4 * 4;
  if (EPI == 1) {  // Sl8 = e4m3(acc * scale), row-major bytes
    unsigned char* C = (unsigned char*)Cv + bz * strC;
#pragma unroll
    for (int ni = 0; ni < 4; ++ni) {
      const int col = n0 + wn * 64 + ni * 16 + l15;
#pragma unroll
      for (int mi = 0; mi < 4; ++mi)
#pragma unroll
        for (int r = 0; r < 4; ++r) {
          const int row = m0 + wm * 64 + mi * 16 + rB + r;
          const float v = acc[mi][ni][r] * scale;
          const unsigned d = __builtin_amdgcn_cvt_pk_fp8_f32(v, v, 0, false);
          C[(long long)row * ldc + col] = (unsigned char)(d & 0xff);
        }
    }
  } else {  // EPI == 2
    float* C = (float*)Cv + bz * strC;
    const float* Xb = X + bz * strX;
#pragma unroll
    for (int ni = 0; ni < 4; ++ni) {
      const int col = n0 + wn * 64 + ni * 16 + l15;
#pragma unroll
      for (int mi = 0; mi < 4; ++mi)
#pragma unroll
        for (int r = 0; r < 4; ++r) {
          const int row = m0 + wm * 64 + mi * 16 + rB + r;
          const long long idx = (long long)row * ldc + col;
          C[idx] = acc[mi][ni][r] * scale + Xb[idx];
        }
    }
  }
}

extern "C" void kernel_launch(void* const* d_in, const int* in_sizes, int n_in,
                              void* d_out, int out_size, void* d_ws, size_t ws_size,
                              hipStream_t stream) {
  const float* x  = (const float*)d_in[0];
  const float* y  = (const float*)d_in[1];
  const float* Wq = (const float*)d_in[2];
  const float* bq = (const float*)d_in[3];
  const float* Wk = (const float*)d_in[4];
  const float* bk = (const float*)d_in[5];
  const float* Wv = (const float*)d_in[6];
  const float* bv = (const float*)d_in[7];
  float* out = (float*)d_out;

  const long long SD  = 2048LL * 1024;
  const long long BSD = 16LL * SD;
  const long long SS  = 2048LL * 2048;

  char* ws = (char*)d_ws;
  short* xb  = (short*)ws;                   // 67.1 MB (yb contiguous after)
  short* yb  = xb + BSD;                     // 67.1 MB
  unsigned char* Sl8 = (unsigned char*)ws;   // 67.1 MB fp8 (aliases xb; dead then)
  unsigned char* Q8 = (unsigned char*)(ws + 134217728);  // 33.5 MB fp8
  unsigned char* K8 = (unsigned char*)(ws + 167772160);  // 33.5 MB fp8 (Q8+stride)
  unsigned char* P8 = Q8;                    // 67.1 MB fp8 (overwrites Q8+K8, both dead)
  unsigned char* V8 = (unsigned char*)(ws + 268435456);  // 33.5 MB fp8
  short* Wqt = (short*)(ws + 335544320);     // 2 MB each, contiguous
  short* Wkt = Wqt + 1024 * 1024;
  short* Wvt = Wkt + 1024 * 1024;

  // 1) convert x, y to bf16 (one dispatch)
  cvt2_k<<<dim3(2048, 1, 2), 256, 0, stream>>>(x, y, xb, yb, (int)(BSD / 4));

  // 2) transpose+convert all three weights (one dispatch)
  cvtT3_k<<<dim3(32, 32, 3), 256, 0, stream>>>(Wq, Wk, Wv, Wqt, Wkt, Wvt);

  // 3+4) Q8/K8 projections batched: z=0: xb@Wqt+bq -> Q8; z=1: yb@Wkt+bk -> K8
  gemm256_k<4><<<dim3(4, 128, 2), 512, 0, stream>>>(
      xb, Wqt, Q8, bq, bk, 1024, 1024, 1024, 1024,
      BSD, 1048576LL, 33554432LL);

  // 5) V8 = e4m3(V^T): A = Wv^T, Bt = yb -> [b][f][G(s)]
  gemm256_k<3><<<dim3(128, 4, 1), 512, 0, stream>>>(
      Wvt, yb, V8, bv, nullptr, 1024, 1024, 1024, 0, 0, 0, 0);

  // 6) Sl8 = e4m3((Q8 @ K8^T)/32)   (fp8 GEMM, K=1024)
  g8fp8_k<1><<<dim3(16, 8, 16), 512, 0, stream>>>(
      Q8, K8, Sl8, nullptr, 1024, 1024, 1024, 2048,
      2097152LL, 2097152LL, SS, 0, 0.03125f);

  // 7) softmax rows (fp8 in) -> P8 = e4m3(256 * P), k-interleaved
  softmax8_k<<<32768, 256, 0, stream>>>(Sl8, P8);

  // 8) out = (P8 @ V8) / 256 + x   (fp8 GEMM, K=2048)
  g8fp8_k<2><<<dim3(8, 8, 16), 512, 0, stream>>>(
      P8, V8, out, x, 2048, 2048, 2048, 1024,
      4194304LL, 2097152LL, SD, SD, 0.00390625f);

  (void)in_sizes; (void)n_in; (void)out_size; (void)ws_size;
}